// Round 5
// baseline (209.204 us; speedup 1.0000x reference)
//
#include <hip/hip_runtime.h>
#include <hip/hip_bf16.h>

#define B_  2
#define S_  2048
#define H_  1024
#define NH_ 16
#define HD_ 64
#define T_  (B_*S_)     // 4096 tokens
#define H3_ (3*H_)      // 3072

typedef float  floatx4 __attribute__((ext_vector_type(4)));
typedef __bf16 bf16x8  __attribute__((ext_vector_type(8)));

__device__ inline unsigned short f2bf_rn(float f) {
    union { float f; unsigned int u; } v; v.f = f;
    unsigned int u = v.u;
    u += 0x7fffu + ((u >> 16) & 1u);
    return (unsigned short)(u >> 16);
}
__device__ inline floatx4 fzero4() { floatx4 v; v[0]=0.f; v[1]=0.f; v[2]=0.f; v[3]=0.f; return v; }

// pack two f32 -> one u32 of two bf16 (lo = src0), RNE; no builtin on gfx950 -> inline asm
__device__ inline unsigned int cvtpk_bf16(float lo, float hi) {
    unsigned int r;
    asm("v_cvt_pk_bf16_f32 %0, %1, %2" : "=v"(r) : "v"(lo), "v"(hi));
    return r;
}
// sum of the two bf16 values inside u (as f32) — keeps denominator consistent with PV operands
__device__ inline float bfsum2(unsigned int u) {
    union { unsigned int i; float f; } a, c;
    a.i = u << 16; c.i = u & 0xffff0000u;
    return a.f + c.f;
}

// async global->LDS, 16B per lane; LDS dest = wave-uniform base + lane*16
__device__ inline void gload_lds16(const unsigned short* g, unsigned short* l) {
    __builtin_amdgcn_global_load_lds((const __attribute__((address_space(1))) unsigned int*)g,
                                     (__attribute__((address_space(3))) unsigned int*)l,
                                     16, 0, 0);
}

// ---------------------------------------------------------------- fused cast + transpose (both weights, one launch)
#define TLD 72
__global__ __launch_bounds__(256) void cvt_both_k(const float* __restrict__ qkvw,
                                                  const float* __restrict__ ow,
                                                  unsigned short* __restrict__ qkvwT,
                                                  unsigned short* __restrict__ owT) {
    __shared__ unsigned short Ts[64 * TLD];
    int id = blockIdx.x;
    const float* W; unsigned short* Wt; int N, nb, kb;
    if (id < 768) { W = qkvw; Wt = qkvwT; N = H3_; nb = (id % 48) * 64; kb = (id / 48) * 64; }
    else { id -= 768; W = ow; Wt = owT; N = H_; nb = (id % 16) * 64; kb = (id / 16) * 64; }
    const int K = H_;
    const int tid = threadIdx.x;
    #pragma unroll
    for (int p = 0; p < 4; p++) {
        const int krow = kb + p * 16 + (tid >> 4);
        const int ncol = (tid & 15) * 4;
        const float4 w = *reinterpret_cast<const float4*>(&W[(size_t)krow * N + nb + ncol]);
        Ts[(ncol + 0) * TLD + p * 16 + (tid >> 4)] = f2bf_rn(w.x);
        Ts[(ncol + 1) * TLD + p * 16 + (tid >> 4)] = f2bf_rn(w.y);
        Ts[(ncol + 2) * TLD + p * 16 + (tid >> 4)] = f2bf_rn(w.z);
        Ts[(ncol + 3) * TLD + p * 16 + (tid >> 4)] = f2bf_rn(w.w);
    }
    __syncthreads();
    #pragma unroll
    for (int p = 0; p < 2; p++) {
        const int n = (tid >> 3) + p * 32;
        const int k8 = (tid & 7) * 8;
        const uint4 v = *reinterpret_cast<const uint4*>(&Ts[n * TLD + k8]);
        *reinterpret_cast<uint4*>(&Wt[(size_t)(nb + n) * K + kb + k8]) = v;
    }
}

// ---------------------------------------------------------------- LayerNorm (fp32 stats, bf16 out)
__global__ __launch_bounds__(256) void layernorm_k(const float* __restrict__ x,
                                                   const float* __restrict__ w,
                                                   const float* __restrict__ b,
                                                   unsigned short* __restrict__ xn) {
    const int t   = blockIdx.x;
    const int tid = threadIdx.x;
    const float4 v = reinterpret_cast<const float4*>(x + (size_t)t * H_)[tid];
    float s  = v.x + v.y + v.z + v.w;
    float s2 = v.x*v.x + v.y*v.y + v.z*v.z + v.w*v.w;
    for (int off = 32; off > 0; off >>= 1) {
        s  += __shfl_down(s,  off, 64);
        s2 += __shfl_down(s2, off, 64);
    }
    __shared__ float red[8];
    const int wave = tid >> 6, lane = tid & 63;
    if (lane == 0) { red[wave] = s; red[4 + wave] = s2; }
    __syncthreads();
    if (tid == 0) {
        red[0] = red[0] + red[1] + red[2] + red[3];
        red[4] = red[4] + red[5] + red[6] + red[7];
    }
    __syncthreads();
    const float mean = red[0] * (1.f / H_);
    const float var  = red[4] * (1.f / H_) - mean * mean;
    const float rstd = rsqrtf(var + 1e-5f);
    const float4 wv = reinterpret_cast<const float4*>(w)[tid];
    const float4 bv = reinterpret_cast<const float4*>(b)[tid];
    ushort4 o = make_ushort4(f2bf_rn((v.x - mean) * rstd * wv.x + bv.x),
                             f2bf_rn((v.y - mean) * rstd * wv.y + bv.y),
                             f2bf_rn((v.z - mean) * rstd * wv.z + bv.z),
                             f2bf_rn((v.w - mean) * rstd * wv.w + bv.w));
    reinterpret_cast<ushort4*>(xn + (size_t)t * H_)[tid] = o;
}

// ---------------------------------------------------------------- shared GEMM core: BK=64 as two BK=32 sub-buffers
#define BM 128
#define BN 128

__device__ inline void gemm_core(const unsigned short* __restrict__ A,
                                 const unsigned short* __restrict__ Bt,
                                 int K, int mBase, int nBase,
                                 int tid, floatx4 acc[4][4],
                                 unsigned short* As0, unsigned short* As1,
                                 unsigned short* Bs0, unsigned short* Bs1) {
    const int lane = tid & 63;
    const int wave = tid >> 6;
    const int wr = wave >> 1, wc = wave & 1;
    const int srow = lane >> 2;        // 0..15
    const int scol = (lane & 3) * 8;   // 0,8,16,24
    const int mrow = lane & 15;
    const int koff = (lane >> 4) * 8;

    for (int kb = 0; kb < K; kb += 64) {
        __syncthreads();
        #pragma unroll
        for (int p = 0; p < 2; p++) {
            const int r = wave * 16 + p * 64;
            const size_t ga = (size_t)(mBase + r + srow) * K + kb + scol;
            const size_t gb = (size_t)(nBase + r + srow) * K + kb + scol;
            gload_lds16(&A [ga],      &As0[r * 32]);
            gload_lds16(&A [ga + 32], &As1[r * 32]);
            gload_lds16(&Bt[gb],      &Bs0[r * 32]);
            gload_lds16(&Bt[gb + 32], &Bs1[r * 32]);
        }
        __syncthreads();

        #pragma unroll
        for (int half = 0; half < 2; half++) {
            const unsigned short* As = half ? As1 : As0;
            const unsigned short* Bs = half ? Bs1 : Bs0;
            bf16x8 afrag[4], bfrag[4];
            #pragma unroll
            for (int mt = 0; mt < 4; mt++)
                afrag[mt] = *reinterpret_cast<const bf16x8*>(&As[(wr * 64 + mt * 16 + mrow) * 32 + koff]);
            #pragma unroll
            for (int nt = 0; nt < 4; nt++)
                bfrag[nt] = *reinterpret_cast<const bf16x8*>(&Bs[(wc * 64 + nt * 16 + mrow) * 32 + koff]);
            #pragma unroll
            for (int mt = 0; mt < 4; mt++)
                #pragma unroll
                for (int nt = 0; nt < 4; nt++)
                    acc[mt][nt] = __builtin_amdgcn_mfma_f32_16x16x32_bf16(afrag[mt], bfrag[nt], acc[mt][nt], 0, 0, 0);
        }
    }
}

// ---------------------------------------------------------------- QKV GEMM with fused bias+rotary+V-transpose epilogue
__global__ __launch_bounds__(256) void gemm_qkv_k(const unsigned short* __restrict__ A,
                                                  const unsigned short* __restrict__ Bt,
                                                  const float* __restrict__ bias,
                                                  unsigned short* __restrict__ Qo,
                                                  unsigned short* __restrict__ Ko,
                                                  unsigned short* __restrict__ Vto) {
    __shared__ unsigned short As0[BM * 32], As1[BM * 32];
    __shared__ unsigned short Bs0[BN * 32], Bs1[BN * 32];

    const int tid  = threadIdx.x;
    const int lane = tid & 63;
    const int wave = tid >> 6;
    const int wr = wave >> 1, wc = wave & 1;
    const int mBase = blockIdx.y * BM;
    const int nBase = blockIdx.x * BN;

    floatx4 acc[4][4];
    #pragma unroll
    for (int i = 0; i < 4; i++)
        #pragma unroll
        for (int j = 0; j < 4; j++) acc[i][j] = fzero4();

    gemm_core(A, Bt, H_, mBase, nBase, tid, acc, As0, As1, Bs0, Bs1);

    const int col0 = lane & 15;
    const int r0   = (lane >> 4) * 4;
    const int hg   = (nBase + wc * 64) >> 6;   // global head index (wave-uniform)
    const int sec  = hg >> 4;                  // 0=q 1=k 2=v
    const int h    = hg & 15;

    float bs[4];
    #pragma unroll
    for (int nt = 0; nt < 4; nt++) bs[nt] = bias[nBase + wc * 64 + nt * 16 + col0];

    if (sec < 2) {
        unsigned short* dst = (sec == 0) ? Qo : Ko;
        const float if0 = __expf((float)col0        * (-0.2878231366f));   // j = col0
        const float if1 = __expf((float)(16 + col0) * (-0.2878231366f));   // j = 16+col0
        #pragma unroll
        for (int mt = 0; mt < 4; mt++) {
            #pragma unroll
            for (int reg = 0; reg < 4; reg++) {
                const int t  = mBase + wr * 64 + mt * 16 + r0 + reg;
                const int bb = t >> 11;
                const int s  = t & (S_ - 1);
                float sn0, cs0, sn1, cs1;
                __sincosf((float)s * if0, &sn0, &cs0);
                __sincosf((float)s * if1, &sn1, &cs1);
                const float v0 = acc[mt][0][reg] + bs[0];   // d = col0
                const float v1 = acc[mt][1][reg] + bs[1];   // d = 16+col0
                const float v2 = acc[mt][2][reg] + bs[2];   // d = 32+col0
                const float v3 = acc[mt][3][reg] + bs[3];   // d = 48+col0
                const float o0 = v0 * cs0 - v2 * sn0;
                const float o1 = v1 * cs1 - v3 * sn1;
                const float o2 = v2 * cs0 + v0 * sn0;
                const float o3 = v3 * cs1 + v1 * sn1;
                const size_t rb = ((size_t)(bb * NH_ + h) * S_ + s) * HD_;
                dst[rb +      col0] = f2bf_rn(o0);
                dst[rb + 16 + col0] = f2bf_rn(o1);
                dst[rb + 32 + col0] = f2bf_rn(o2);
                dst[rb + 48 + col0] = f2bf_rn(o3);
            }
        }
    } else {
        #pragma unroll
        for (int mt = 0; mt < 4; mt++) {
            const int t0 = mBase + wr * 64 + mt * 16 + r0;   // 4 consecutive tokens, 4-aligned
            const int bb = t0 >> 11;
            const int s0 = t0 & (S_ - 1);
            #pragma unroll
            for (int nt = 0; nt < 4; nt++) {
                const int d = nt * 16 + col0;
                ushort4 o;
                o.x = f2bf_rn(acc[mt][nt][0] + bs[nt]);
                o.y = f2bf_rn(acc[mt][nt][1] + bs[nt]);
                o.z = f2bf_rn(acc[mt][nt][2] + bs[nt]);
                o.w = f2bf_rn(acc[mt][nt][3] + bs[nt]);
                *reinterpret_cast<ushort4*>(&Vto[((size_t)(bb * NH_ + h) * HD_ + d) * S_ + s0]) = o;
            }
        }
    }
}

// ---------------------------------------------------------------- proj GEMM: C = A @ Bt^T + bias (f32 out)
__global__ __launch_bounds__(256) void gemm_proj_k(const unsigned short* __restrict__ A,
                                                   const unsigned short* __restrict__ Bt,
                                                   const float* __restrict__ bias,
                                                   float* __restrict__ Cf,
                                                   int M, int N, int K) {
    __shared__ unsigned short As0[BM * 32], As1[BM * 32];
    __shared__ unsigned short Bs0[BN * 32], Bs1[BN * 32];

    const int tid  = threadIdx.x;
    const int lane = tid & 63;
    const int wave = tid >> 6;
    const int wr = wave >> 1, wc = wave & 1;
    const int mBase = blockIdx.y * BM;
    const int nBase = blockIdx.x * BN;

    floatx4 acc[4][4];
    #pragma unroll
    for (int i = 0; i < 4; i++)
        #pragma unroll
        for (int j = 0; j < 4; j++) acc[i][j] = fzero4();

    gemm_core(A, Bt, K, mBase, nBase, tid, acc, As0, As1, Bs0, Bs1);

    const int col0 = lane & 15;
    const int r0   = (lane >> 4) * 4;
    #pragma unroll
    for (int mt = 0; mt < 4; mt++) {
        #pragma unroll
        for (int nt = 0; nt < 4; nt++) {
            const int gcol = nBase + wc * 64 + nt * 16 + col0;
            const float bsv = bias[gcol];
            #pragma unroll
            for (int reg = 0; reg < 4; reg++) {
                const int grow = mBase + wr * 64 + mt * 16 + r0 + reg;
                Cf[(size_t)grow * N + gcol] = acc[mt][nt][reg] + bsv;
            }
        }
    }
}

// ---------------------------------------------------------------- flash attention: in-register P (swapped QK + key-permuted K staging)
// St = mfma(kf, qf) puts S^T in regs (lane: key-quad x q=lane&15). K tile is staged with keys
// PERMUTED per 32-window (LDS row r <-> key 8*((r&12)>>2)+(r&3)+4*((r>>4)&1)) so the four St
// quads per lane are exactly the 8-consecutive-key groups the PV B-fragment needs: P never
// touches LDS — 8 cvt_pk build PV operands straight from accumulators. Softmax is key-order
// invariant; V / mask / causal use true key ids. Denominator = unpack-sum of the same bf16
// values fed to PV (consistent), reduced cross-lane once in the epilogue. No Ps LDS ->
// 36.9KB, 4 blocks/CU. r0 skeleton otherwise (4-wave blocks, reg prefetch, 2 barriers/128 keys).
#define ALD 72
#define SCL2 0.1803368801f      /* 0.125 * log2(e) */
#define MNEG -14427.0f          /* -10000 * log2(e), causal fill */

__global__ __launch_bounds__(256, 4) void attn_k(const unsigned short* __restrict__ Q,
                                                 const unsigned short* __restrict__ Kg,
                                                 const unsigned short* __restrict__ Vt,
                                                 const int* __restrict__ mask,
                                                 unsigned short* __restrict__ ctx) {
    const int id = blockIdx.x;              // 0..1023
    const int bh = id & 31;                 // id%8 fixed per bh -> XCD locality
    const int v  = 31 - (id >> 5);          // q-tile index; most work first
    const int b  = bh >> 4;
    const int h  = bh & 15;
    const int tid  = threadIdx.x;
    const int lane = tid & 63;
    const int wave = tid >> 6;

    __shared__ unsigned short Ks [2][64 * ALD];   // 18.4 KB (key-permuted rows)
    __shared__ unsigned short Vts[2][64 * ALD];   // 18.4 KB (natural key order)

    const size_t base = (size_t)bh * S_ * HD_;
    const int qbase = v * 64 + wave * 16;
    const int r16  = lane & 15;             // A-row / output-col lane index
    const int koff = (lane >> 4) * 8;       // d-offset in fragments / key-offset in PV reads
    const int g8   = (lane >> 4) * 8;       // key-group base for St quads
    const int qcol = qbase + r16;           // this lane's q row (output column)

    const bf16x8 qf0 = *reinterpret_cast<const bf16x8*>(&Q[base + (size_t)(qbase + r16) * HD_ + koff]);
    const bf16x8 qf1 = *reinterpret_cast<const bf16x8*>(&Q[base + (size_t)(qbase + r16) * HD_ + 32 + koff]);

    floatx4 Ot[4];                           // O^T: lane holds O^T[d=db*16+(lane>>4)*4+reg][q=qcol]
    #pragma unroll
    for (int db = 0; db < 4; db++) Ot[db] = fzero4();
    float Lp = 0.f;                          // partial row-sum over this lane's key groups

    const int srow = tid >> 3;          // 0..31
    const int scol = (tid & 7) * 8;
    // key permutation within a 32-window: row r holds key pi(r)
    const int pi = ((srow & 12) << 1) | (srow & 3) | (((srow >> 4) & 1) << 2);

    // named prefetch registers for 2 tiles (no runtime-indexed arrays -> no scratch)
    uint4 k00, k01, k10, k11, v00, v01, v10, v11;
#define PF_TILE(TT, KR0, KR1, VR0, VR1) do {                                                   \
        const int kb_ = (TT) * 64;                                                             \
        KR0 = *reinterpret_cast<const uint4*>(&Kg[base + (size_t)(kb_ + pi)      * HD_ + scol]); \
        KR1 = *reinterpret_cast<const uint4*>(&Kg[base + (size_t)(kb_ + 32 + pi) * HD_ + scol]); \
        VR0 = *reinterpret_cast<const uint4*>(&Vt[base + (size_t)srow        * S_ + kb_ + scol]);  \
        VR1 = *reinterpret_cast<const uint4*>(&Vt[base + (size_t)(srow + 32) * S_ + kb_ + scol]);  \
    } while (0)
#define PREFETCH_MACRO(MI) do {                                                                \
        const int t0_ = min(2 * (MI), v);                                                      \
        const int t1_ = min(2 * (MI) + 1, v);                                                  \
        PF_TILE(t0_, k00, k01, v00, v01);                                                      \
        PF_TILE(t1_, k10, k11, v10, v11);                                                      \
    } while (0)

    const int nmac = (v + 2) >> 1;
    PREFETCH_MACRO(0);

    for (int mi = 0; mi < nmac; mi++) {
        if (mi) __syncthreads();                       // WAR: prior macro's LDS reads done
        *reinterpret_cast<uint4*>(&Ks [0][ srow       * ALD + scol]) = k00;
        *reinterpret_cast<uint4*>(&Ks [0][(srow + 32) * ALD + scol]) = k01;
        *reinterpret_cast<uint4*>(&Ks [1][ srow       * ALD + scol]) = k10;
        *reinterpret_cast<uint4*>(&Ks [1][(srow + 32) * ALD + scol]) = k11;
        *reinterpret_cast<uint4*>(&Vts[0][ srow       * ALD + scol]) = v00;
        *reinterpret_cast<uint4*>(&Vts[0][(srow + 32) * ALD + scol]) = v01;
        *reinterpret_cast<uint4*>(&Vts[1][ srow       * ALD + scol]) = v10;
        *reinterpret_cast<uint4*>(&Vts[1][(srow + 32) * ALD + scol]) = v11;
        __syncthreads();                               // staged tiles visible
        if (mi + 1 < nmac) PREFETCH_MACRO(mi + 1);

        #pragma unroll
        for (int half = 0; half < 2; half++) {
            const int kt = 2 * mi + half;
            if (half && kt > v) continue;              // wave-uniform skip (odd tile count)
            const int kb = kt * 64;
            const unsigned short* ks = Ks [half];
            const unsigned short* vs = Vts[half];

            #pragma unroll
            for (int w = 0; w < 2; w++) {              // two 32-key windows
                float p[2][4];
                #pragma unroll
                for (int ab = 0; ab < 2; ab++) {
                    const int nt = w * 2 + ab;
                    // St = K·Q^T over permuted K rows; quad reg -> key kb + w*32 + ab*4 + 8g + reg
                    const bf16x8 kf0 = *reinterpret_cast<const bf16x8*>(&ks[(nt * 16 + r16) * ALD + koff]);
                    const bf16x8 kf1 = *reinterpret_cast<const bf16x8*>(&ks[(nt * 16 + r16) * ALD + 32 + koff]);
                    floatx4 c = fzero4();
                    c = __builtin_amdgcn_mfma_f32_16x16x32_bf16(kf0, qf0, c, 0, 0, 0);
                    c = __builtin_amdgcn_mfma_f32_16x16x32_bf16(kf1, qf1, c, 0, 0, 0);
                    const int kbase = kb + w * 32 + ab * 4 + g8;
                    const int4 mm = *reinterpret_cast<const int4*>(&mask[b * S_ + kbase]);
                    float sc0 = c[0] * SCL2 + (1.f - (float)mm.x) * MNEG;
                    float sc1 = c[1] * SCL2 + (1.f - (float)mm.y) * MNEG;
                    float sc2 = c[2] * SCL2 + (1.f - (float)mm.z) * MNEG;
                    float sc3 = c[3] * SCL2 + (1.f - (float)mm.w) * MNEG;
                    if (kt == v) {                     // causal on diagonal tile only
                        if (kbase + 0 > qcol) sc0 = MNEG;
                        if (kbase + 1 > qcol) sc1 = MNEG;
                        if (kbase + 2 > qcol) sc2 = MNEG;
                        if (kbase + 3 > qcol) sc3 = MNEG;
                    }
                    p[ab][0] = exp2f(sc0);
                    p[ab][1] = exp2f(sc1);
                    p[ab][2] = exp2f(sc2);
                    p[ab][3] = exp2f(sc3);
                }
                // pack P fragment: keys w*32 + 8g + {0..7} in order
                const unsigned int u0 = cvtpk_bf16(p[0][0], p[0][1]);
                const unsigned int u1 = cvtpk_bf16(p[0][2], p[0][3]);
                const unsigned int u2 = cvtpk_bf16(p[1][0], p[1][1]);
                const unsigned int u3 = cvtpk_bf16(p[1][2], p[1][3]);
                Lp += (bfsum2(u0) + bfsum2(u1)) + (bfsum2(u2) + bfsum2(u3));
                union { uint4 u; bf16x8 v; } pf;
                pf.u.x = u0; pf.u.y = u1; pf.u.z = u2; pf.u.w = u3;
                // PV: O^T += V^T · P^T (V natural key order, contiguous reads)
                #pragma unroll
                for (int db = 0; db < 4; db++) {
                    const bf16x8 vf = *reinterpret_cast<const bf16x8*>(&vs[(db * 16 + r16) * ALD + w * 32 + koff]);
                    Ot[db] = __builtin_amdgcn_mfma_f32_16x16x32_bf16(vf, pf.v, Ot[db], 0, 0, 0);
                }
            }
        }
    }
#undef PREFETCH_MACRO
#undef PF_TILE

    // epilogue: complete the row sum across the 4 key-quad lane groups, then scale + store O^T
    float lsum = Lp;
    lsum += __shfl_xor(lsum, 16, 64);
    lsum += __shfl_xor(lsum, 32, 64);
    const float rl = 1.f / lsum;
    const int r4 = (lane >> 4) * 4;
    #pragma unroll
    for (int db = 0; db < 4; db++) {
        ushort4 o;
        o.x = f2bf_rn(Ot[db][0] * rl);
        o.y = f2bf_rn(Ot[db][1] * rl);
        o.z = f2bf_rn(Ot[db][2] * rl);
        o.w = f2bf_rn(Ot[db][3] * rl);
        *reinterpret_cast<ushort4*>(&ctx[((size_t)b * S_ + qcol) * H_ + h * HD_ + db * 16 + r4]) = o;
    }
}

// ---------------------------------------------------------------- launch
extern "C" void kernel_launch(void* const* d_in, const int* in_sizes, int n_in,
                              void* d_out, int out_size, void* d_ws, size_t ws_size,
                              hipStream_t stream) {
    const float* x     = (const float*)d_in[0];
    const int*   mask  = (const int*)d_in[1];
    const float* normw = (const float*)d_in[2];
    const float* normb = (const float*)d_in[3];
    const float* qkvw  = (const float*)d_in[4];
    const float* qkvb  = (const float*)d_in[5];
    const float* ow    = (const float*)d_in[6];
    const float* ob    = (const float*)d_in[7];
    float* out = (float*)d_out;

    char* ws = (char*)d_ws;
    unsigned short* xn_bf   = (unsigned short*)(ws);                      //  8 MB
    unsigned short* qkvwT   = (unsigned short*)(ws + (8ull  << 20));      //  6 MB
    unsigned short* owT     = (unsigned short*)(ws + (14ull << 20));      //  2 MB
    unsigned short* Qb      = (unsigned short*)(ws + (16ull << 20));      //  8 MB [bh][s][d]
    unsigned short* Kb      = (unsigned short*)(ws + (24ull << 20));      //  8 MB [bh][s][d]
    unsigned short* Vtb     = (unsigned short*)(ws + (32ull << 20));      //  8 MB [bh][d][s]
    unsigned short* ctx_bf  = (unsigned short*)(ws + (40ull << 20));      //  8 MB

    cvt_both_k<<<1024, 256, 0, stream>>>(qkvw, ow, qkvwT, owT);
    layernorm_k<<<T_, 256, 0, stream>>>(x, normw, normb, xn_bf);
    gemm_qkv_k<<<dim3(H3_ / BN, T_ / BM), 256, 0, stream>>>(xn_bf, qkvwT, qkvb, Qb, Kb, Vtb);
    attn_k<<<1024, 256, 0, stream>>>(Qb, Kb, Vtb, mask, ctx_bf);
    gemm_proj_k<<<dim3(H_ / BN, T_ / BM), 256, 0, stream>>>(ctx_bf, owT, ob, out, T_, H_, H_);
}

// Round 6
// 197.250 us; speedup vs baseline: 1.0606x; 1.0606x over previous
//
#include <hip/hip_runtime.h>
#include <hip/hip_bf16.h>

#define B_  2
#define S_  2048
#define H_  1024
#define NH_ 16
#define HD_ 64
#define T_  (B_*S_)     // 4096 tokens
#define H3_ (3*H_)      // 3072

typedef float  floatx4 __attribute__((ext_vector_type(4)));
typedef __bf16 bf16x8  __attribute__((ext_vector_type(8)));

__device__ inline unsigned short f2bf_rn(float f) {
    union { float f; unsigned int u; } v; v.f = f;
    unsigned int u = v.u;
    u += 0x7fffu + ((u >> 16) & 1u);
    return (unsigned short)(u >> 16);
}
__device__ inline floatx4 fzero4() { floatx4 v; v[0]=0.f; v[1]=0.f; v[2]=0.f; v[3]=0.f; return v; }

__device__ inline float bf2f(unsigned short u) {
    union { unsigned int i; float f; } x; x.i = ((unsigned int)u) << 16; return x.f;
}

// pack two f32 -> one u32 of two bf16 (lo = src0), RNE; no builtin on gfx950 -> inline asm
__device__ inline unsigned int cvtpk_bf16(float lo, float hi) {
    unsigned int r;
    asm("v_cvt_pk_bf16_f32 %0, %1, %2" : "=v"(r) : "v"(lo), "v"(hi));
    return r;
}
// sum of the two bf16 values inside u (as f32) — keeps denominator consistent with PV operands
__device__ inline float bfsum2(unsigned int u) {
    union { unsigned int i; float f; } a, c;
    a.i = u << 16; c.i = u & 0xffff0000u;
    return a.f + c.f;
}

// async global->LDS, 16B per lane; LDS dest = wave-uniform base + lane*16
__device__ inline void gload_lds16(const unsigned short* g, unsigned short* l) {
    __builtin_amdgcn_global_load_lds((const __attribute__((address_space(1))) unsigned int*)g,
                                     (__attribute__((address_space(3))) unsigned int*)l,
                                     16, 0, 0);
}

// ---------------------------------------------------------------- fused cast + transpose (both weights, one launch)
#define TLD 72
__global__ __launch_bounds__(256) void cvt_both_k(const float* __restrict__ qkvw,
                                                  const float* __restrict__ ow,
                                                  unsigned short* __restrict__ qkvwT,
                                                  unsigned short* __restrict__ owT) {
    __shared__ unsigned short Ts[64 * TLD];
    int id = blockIdx.x;
    const float* W; unsigned short* Wt; int N, nb, kb;
    if (id < 768) { W = qkvw; Wt = qkvwT; N = H3_; nb = (id % 48) * 64; kb = (id / 48) * 64; }
    else { id -= 768; W = ow; Wt = owT; N = H_; nb = (id % 16) * 64; kb = (id / 16) * 64; }
    const int K = H_;
    const int tid = threadIdx.x;
    #pragma unroll
    for (int p = 0; p < 4; p++) {
        const int krow = kb + p * 16 + (tid >> 4);
        const int ncol = (tid & 15) * 4;
        const float4 w = *reinterpret_cast<const float4*>(&W[(size_t)krow * N + nb + ncol]);
        Ts[(ncol + 0) * TLD + p * 16 + (tid >> 4)] = f2bf_rn(w.x);
        Ts[(ncol + 1) * TLD + p * 16 + (tid >> 4)] = f2bf_rn(w.y);
        Ts[(ncol + 2) * TLD + p * 16 + (tid >> 4)] = f2bf_rn(w.z);
        Ts[(ncol + 3) * TLD + p * 16 + (tid >> 4)] = f2bf_rn(w.w);
    }
    __syncthreads();
    #pragma unroll
    for (int p = 0; p < 2; p++) {
        const int n = (tid >> 3) + p * 32;
        const int k8 = (tid & 7) * 8;
        const uint4 v = *reinterpret_cast<const uint4*>(&Ts[n * TLD + k8]);
        *reinterpret_cast<uint4*>(&Wt[(size_t)(nb + n) * K + kb + k8]) = v;
    }
}

// ---------------------------------------------------------------- LayerNorm (fp32 stats, bf16 out)
__global__ __launch_bounds__(256) void layernorm_k(const float* __restrict__ x,
                                                   const float* __restrict__ w,
                                                   const float* __restrict__ b,
                                                   unsigned short* __restrict__ xn) {
    const int t   = blockIdx.x;
    const int tid = threadIdx.x;
    const float4 v = reinterpret_cast<const float4*>(x + (size_t)t * H_)[tid];
    float s  = v.x + v.y + v.z + v.w;
    float s2 = v.x*v.x + v.y*v.y + v.z*v.z + v.w*v.w;
    for (int off = 32; off > 0; off >>= 1) {
        s  += __shfl_down(s,  off, 64);
        s2 += __shfl_down(s2, off, 64);
    }
    __shared__ float red[8];
    const int wave = tid >> 6, lane = tid & 63;
    if (lane == 0) { red[wave] = s; red[4 + wave] = s2; }
    __syncthreads();
    if (tid == 0) {
        red[0] = red[0] + red[1] + red[2] + red[3];
        red[4] = red[4] + red[5] + red[6] + red[7];
    }
    __syncthreads();
    const float mean = red[0] * (1.f / H_);
    const float var  = red[4] * (1.f / H_) - mean * mean;
    const float rstd = rsqrtf(var + 1e-5f);
    const float4 wv = reinterpret_cast<const float4*>(w)[tid];
    const float4 bv = reinterpret_cast<const float4*>(b)[tid];
    ushort4 o = make_ushort4(f2bf_rn((v.x - mean) * rstd * wv.x + bv.x),
                             f2bf_rn((v.y - mean) * rstd * wv.y + bv.y),
                             f2bf_rn((v.z - mean) * rstd * wv.z + bv.z),
                             f2bf_rn((v.w - mean) * rstd * wv.w + bv.w));
    reinterpret_cast<ushort4*>(xn + (size_t)t * H_)[tid] = o;
}

// ---------------------------------------------------------------- shared GEMM core: BK=64 as two BK=32 sub-buffers
#define BM 128
#define BN 128

__device__ inline void gemm_core(const unsigned short* __restrict__ A,
                                 const unsigned short* __restrict__ Bt,
                                 int K, int mBase, int nBase,
                                 int tid, floatx4 acc[4][4],
                                 unsigned short* As0, unsigned short* As1,
                                 unsigned short* Bs0, unsigned short* Bs1) {
    const int lane = tid & 63;
    const int wave = tid >> 6;
    const int wr = wave >> 1, wc = wave & 1;
    const int srow = lane >> 2;        // 0..15
    const int scol = (lane & 3) * 8;   // 0,8,16,24
    const int mrow = lane & 15;
    const int koff = (lane >> 4) * 8;

    for (int kb = 0; kb < K; kb += 64) {
        __syncthreads();
        #pragma unroll
        for (int p = 0; p < 2; p++) {
            const int r = wave * 16 + p * 64;
            const size_t ga = (size_t)(mBase + r + srow) * K + kb + scol;
            const size_t gb = (size_t)(nBase + r + srow) * K + kb + scol;
            gload_lds16(&A [ga],      &As0[r * 32]);
            gload_lds16(&A [ga + 32], &As1[r * 32]);
            gload_lds16(&Bt[gb],      &Bs0[r * 32]);
            gload_lds16(&Bt[gb + 32], &Bs1[r * 32]);
        }
        __syncthreads();

        #pragma unroll
        for (int half = 0; half < 2; half++) {
            const unsigned short* As = half ? As1 : As0;
            const unsigned short* Bs = half ? Bs1 : Bs0;
            bf16x8 afrag[4], bfrag[4];
            #pragma unroll
            for (int mt = 0; mt < 4; mt++)
                afrag[mt] = *reinterpret_cast<const bf16x8*>(&As[(wr * 64 + mt * 16 + mrow) * 32 + koff]);
            #pragma unroll
            for (int nt = 0; nt < 4; nt++)
                bfrag[nt] = *reinterpret_cast<const bf16x8*>(&Bs[(wc * 64 + nt * 16 + mrow) * 32 + koff]);
            #pragma unroll
            for (int mt = 0; mt < 4; mt++)
                #pragma unroll
                for (int nt = 0; nt < 4; nt++)
                    acc[mt][nt] = __builtin_amdgcn_mfma_f32_16x16x32_bf16(afrag[mt], bfrag[nt], acc[mt][nt], 0, 0, 0);
        }
    }
}

// ---------------------------------------------------------------- QKV GEMM with fused bias+rotary+V-transpose epilogue
__global__ __launch_bounds__(256) void gemm_qkv_k(const unsigned short* __restrict__ A,
                                                  const unsigned short* __restrict__ Bt,
                                                  const float* __restrict__ bias,
                                                  unsigned short* __restrict__ Qo,
                                                  unsigned short* __restrict__ Ko,
                                                  unsigned short* __restrict__ Vto) {
    __shared__ unsigned short As0[BM * 32], As1[BM * 32];
    __shared__ unsigned short Bs0[BN * 32], Bs1[BN * 32];

    const int tid  = threadIdx.x;
    const int lane = tid & 63;
    const int wave = tid >> 6;
    const int wr = wave >> 1, wc = wave & 1;
    const int mBase = blockIdx.y * BM;
    const int nBase = blockIdx.x * BN;

    floatx4 acc[4][4];
    #pragma unroll
    for (int i = 0; i < 4; i++)
        #pragma unroll
        for (int j = 0; j < 4; j++) acc[i][j] = fzero4();

    gemm_core(A, Bt, H_, mBase, nBase, tid, acc, As0, As1, Bs0, Bs1);

    const int col0 = lane & 15;
    const int r0   = (lane >> 4) * 4;
    const int hg   = (nBase + wc * 64) >> 6;   // global head index (wave-uniform)
    const int sec  = hg >> 4;                  // 0=q 1=k 2=v
    const int h    = hg & 15;

    float bs[4];
    #pragma unroll
    for (int nt = 0; nt < 4; nt++) bs[nt] = bias[nBase + wc * 64 + nt * 16 + col0];

    if (sec < 2) {
        unsigned short* dst = (sec == 0) ? Qo : Ko;
        const float if0 = __expf((float)col0        * (-0.2878231366f));   // j = col0
        const float if1 = __expf((float)(16 + col0) * (-0.2878231366f));   // j = 16+col0
        #pragma unroll
        for (int mt = 0; mt < 4; mt++) {
            #pragma unroll
            for (int reg = 0; reg < 4; reg++) {
                const int t  = mBase + wr * 64 + mt * 16 + r0 + reg;
                const int bb = t >> 11;
                const int s  = t & (S_ - 1);
                float sn0, cs0, sn1, cs1;
                __sincosf((float)s * if0, &sn0, &cs0);
                __sincosf((float)s * if1, &sn1, &cs1);
                const float v0 = acc[mt][0][reg] + bs[0];   // d = col0
                const float v1 = acc[mt][1][reg] + bs[1];   // d = 16+col0
                const float v2 = acc[mt][2][reg] + bs[2];   // d = 32+col0
                const float v3 = acc[mt][3][reg] + bs[3];   // d = 48+col0
                const float o0 = v0 * cs0 - v2 * sn0;
                const float o1 = v1 * cs1 - v3 * sn1;
                const float o2 = v2 * cs0 + v0 * sn0;
                const float o3 = v3 * cs1 + v1 * sn1;
                const size_t rb = ((size_t)(bb * NH_ + h) * S_ + s) * HD_;
                dst[rb +      col0] = f2bf_rn(o0);
                dst[rb + 16 + col0] = f2bf_rn(o1);
                dst[rb + 32 + col0] = f2bf_rn(o2);
                dst[rb + 48 + col0] = f2bf_rn(o3);
            }
        }
    } else {
        #pragma unroll
        for (int mt = 0; mt < 4; mt++) {
            const int t0 = mBase + wr * 64 + mt * 16 + r0;   // 4 consecutive tokens, 4-aligned
            const int bb = t0 >> 11;
            const int s0 = t0 & (S_ - 1);
            #pragma unroll
            for (int nt = 0; nt < 4; nt++) {
                const int d = nt * 16 + col0;
                ushort4 o;
                o.x = f2bf_rn(acc[mt][nt][0] + bs[nt]);
                o.y = f2bf_rn(acc[mt][nt][1] + bs[nt]);
                o.z = f2bf_rn(acc[mt][nt][2] + bs[nt]);
                o.w = f2bf_rn(acc[mt][nt][3] + bs[nt]);
                *reinterpret_cast<ushort4*>(&Vto[((size_t)(bb * NH_ + h) * HD_ + d) * S_ + s0]) = o;
            }
        }
    }
}

// ---------------------------------------------------------------- proj GEMM: C = A @ Bt^T + bias (f32 out)
__global__ __launch_bounds__(256) void gemm_proj_k(const unsigned short* __restrict__ A,
                                                   const unsigned short* __restrict__ Bt,
                                                   const float* __restrict__ bias,
                                                   float* __restrict__ Cf,
                                                   int M, int N, int K) {
    __shared__ unsigned short As0[BM * 32], As1[BM * 32];
    __shared__ unsigned short Bs0[BN * 32], Bs1[BN * 32];

    const int tid  = threadIdx.x;
    const int lane = tid & 63;
    const int wave = tid >> 6;
    const int wr = wave >> 1, wc = wave & 1;
    const int mBase = blockIdx.y * BM;
    const int nBase = blockIdx.x * BN;

    floatx4 acc[4][4];
    #pragma unroll
    for (int i = 0; i < 4; i++)
        #pragma unroll
        for (int j = 0; j < 4; j++) acc[i][j] = fzero4();

    gemm_core(A, Bt, K, mBase, nBase, tid, acc, As0, As1, Bs0, Bs1);

    const int col0 = lane & 15;
    const int r0   = (lane >> 4) * 4;
    #pragma unroll
    for (int mt = 0; mt < 4; mt++) {
        #pragma unroll
        for (int nt = 0; nt < 4; nt++) {
            const int gcol = nBase + wc * 64 + nt * 16 + col0;
            const float bsv = bias[gcol];
            #pragma unroll
            for (int reg = 0; reg < 4; reg++) {
                const int grow = mBase + wr * 64 + mt * 16 + r0 + reg;
                Cf[(size_t)grow * N + gcol] = acc[mt][nt][reg] + bsv;
            }
        }
    }
}

// ---------------------------------------------------------------- flash attention: in-register P + LDS mask-bias table
// r5 structure (swapped QK, key-permuted K staging, P built in-register via cvt_pk — verified) with
// the r5 regression fixed: mask bias precomputed ONCE per block into a 4KB bf16 LDS table (covered
// by the first staging barrier) and read per tile as four 8B broadcast ds_reads issued at half-top,
// ~120cy latency hidden under K-frag reads + 8 QK MFMAs. No global loads and no LDS round-trip in
// the per-tile chain. LDS = 18432(K) + 18432(V) + 4096(bias) = 40960B exactly -> 4 blocks/CU,
// 16 waves/CU (VGPR ~70 <= 128 cap).
#define ALD 72
#define SCL2 0.1803368801f      /* 0.125 * log2(e) */
#define MNEG -14427.0f          /* -10000 * log2(e), causal fill */

__global__ __launch_bounds__(256, 4) void attn_k(const unsigned short* __restrict__ Q,
                                                 const unsigned short* __restrict__ Kg,
                                                 const unsigned short* __restrict__ Vt,
                                                 const int* __restrict__ mask,
                                                 unsigned short* __restrict__ ctx) {
    const int id = blockIdx.x;              // 0..1023
    const int bh = id & 31;                 // id%8 fixed per bh -> XCD locality
    const int v  = 31 - (id >> 5);          // q-tile index; most work first
    const int b  = bh >> 4;
    const int h  = bh & 15;
    const int tid  = threadIdx.x;
    const int lane = tid & 63;
    const int wave = tid >> 6;

    __shared__ unsigned short Ks [2][64 * ALD];   // 18.4 KB (key-permuted rows)
    __shared__ unsigned short Vts[2][64 * ALD];   // 18.4 KB (natural key order)
    __shared__ unsigned short Mb [S_];            //  4.0 KB bf16 mask-bias per key

    const size_t base = (size_t)bh * S_ * HD_;
    const int qbase = v * 64 + wave * 16;
    const int r16  = lane & 15;             // A-row / output-col lane index
    const int koff = (lane >> 4) * 8;       // d-offset in fragments / key-offset in PV reads
    const int g8   = (lane >> 4) * 8;       // key-group base for St quads
    const int qcol = qbase + r16;           // this lane's q row (output column)

    // ---- mask-bias table: 8 keys per thread, one b128 store; visible after first barrier
    {
        const int k0 = tid * 8;
        const int4 ma = *reinterpret_cast<const int4*>(&mask[b * S_ + k0]);
        const int4 mc = *reinterpret_cast<const int4*>(&mask[b * S_ + k0 + 4]);
        union { unsigned short us[8]; uint4 q; } pk;
        pk.us[0] = f2bf_rn((1.f - (float)ma.x) * MNEG);
        pk.us[1] = f2bf_rn((1.f - (float)ma.y) * MNEG);
        pk.us[2] = f2bf_rn((1.f - (float)ma.z) * MNEG);
        pk.us[3] = f2bf_rn((1.f - (float)ma.w) * MNEG);
        pk.us[4] = f2bf_rn((1.f - (float)mc.x) * MNEG);
        pk.us[5] = f2bf_rn((1.f - (float)mc.y) * MNEG);
        pk.us[6] = f2bf_rn((1.f - (float)mc.z) * MNEG);
        pk.us[7] = f2bf_rn((1.f - (float)mc.w) * MNEG);
        *reinterpret_cast<uint4*>(&Mb[k0]) = pk.q;
    }

    const bf16x8 qf0 = *reinterpret_cast<const bf16x8*>(&Q[base + (size_t)(qbase + r16) * HD_ + koff]);
    const bf16x8 qf1 = *reinterpret_cast<const bf16x8*>(&Q[base + (size_t)(qbase + r16) * HD_ + 32 + koff]);

    floatx4 Ot[4];                           // O^T: lane holds O^T[d=db*16+(lane>>4)*4+reg][q=qcol]
    #pragma unroll
    for (int db = 0; db < 4; db++) Ot[db] = fzero4();
    float Lp = 0.f;                          // partial row-sum over this lane's key groups

    const int srow = tid >> 3;          // 0..31
    const int scol = (tid & 7) * 8;
    // key permutation within a 32-window: row r holds key pi(r)
    const int pi = ((srow & 12) << 1) | (srow & 3) | (((srow >> 4) & 1) << 2);

    // named prefetch registers for 2 tiles (no runtime-indexed arrays -> no scratch)
    uint4 k00, k01, k10, k11, v00, v01, v10, v11;
#define PF_TILE(TT, KR0, KR1, VR0, VR1) do {                                                   \
        const int kb_ = (TT) * 64;                                                             \
        KR0 = *reinterpret_cast<const uint4*>(&Kg[base + (size_t)(kb_ + pi)      * HD_ + scol]); \
        KR1 = *reinterpret_cast<const uint4*>(&Kg[base + (size_t)(kb_ + 32 + pi) * HD_ + scol]); \
        VR0 = *reinterpret_cast<const uint4*>(&Vt[base + (size_t)srow        * S_ + kb_ + scol]);  \
        VR1 = *reinterpret_cast<const uint4*>(&Vt[base + (size_t)(srow + 32) * S_ + kb_ + scol]);  \
    } while (0)
#define PREFETCH_MACRO(MI) do {                                                                \
        const int t0_ = min(2 * (MI), v);                                                      \
        const int t1_ = min(2 * (MI) + 1, v);                                                  \
        PF_TILE(t0_, k00, k01, v00, v01);                                                      \
        PF_TILE(t1_, k10, k11, v10, v11);                                                      \
    } while (0)

    const int nmac = (v + 2) >> 1;
    PREFETCH_MACRO(0);

    for (int mi = 0; mi < nmac; mi++) {
        if (mi) __syncthreads();                       // WAR: prior macro's LDS reads done
        *reinterpret_cast<uint4*>(&Ks [0][ srow       * ALD + scol]) = k00;
        *reinterpret_cast<uint4*>(&Ks [0][(srow + 32) * ALD + scol]) = k01;
        *reinterpret_cast<uint4*>(&Ks [1][ srow       * ALD + scol]) = k10;
        *reinterpret_cast<uint4*>(&Ks [1][(srow + 32) * ALD + scol]) = k11;
        *reinterpret_cast<uint4*>(&Vts[0][ srow       * ALD + scol]) = v00;
        *reinterpret_cast<uint4*>(&Vts[0][(srow + 32) * ALD + scol]) = v01;
        *reinterpret_cast<uint4*>(&Vts[1][ srow       * ALD + scol]) = v10;
        *reinterpret_cast<uint4*>(&Vts[1][(srow + 32) * ALD + scol]) = v11;
        __syncthreads();                               // staged tiles + (mi==0) Mb table visible
        if (mi + 1 < nmac) PREFETCH_MACRO(mi + 1);

        #pragma unroll
        for (int half = 0; half < 2; half++) {
            const int kt = 2 * mi + half;
            if (half && kt > v) continue;              // wave-uniform skip (odd tile count)
            const int kb = kt * 64;
            const unsigned short* ks = Ks [half];
            const unsigned short* vs = Vts[half];

            // ---- per-tile bias: four 8B broadcast LDS reads, latency hidden under QK
            const unsigned short* mbp = &Mb[kb + g8];
            const ushort4 b00 = *reinterpret_cast<const ushort4*>(mbp);        // w0 ab0
            const ushort4 b01 = *reinterpret_cast<const ushort4*>(mbp + 4);    // w0 ab1
            const ushort4 b10 = *reinterpret_cast<const ushort4*>(mbp + 32);   // w1 ab0
            const ushort4 b11 = *reinterpret_cast<const ushort4*>(mbp + 36);   // w1 ab1

            #pragma unroll
            for (int w = 0; w < 2; w++) {              // two 32-key windows
                float p[2][4];
                #pragma unroll
                for (int ab = 0; ab < 2; ab++) {
                    const int nt = w * 2 + ab;
                    // St = K·Q^T over permuted K rows; quad reg -> key kb + w*32 + ab*4 + 8g + reg
                    const bf16x8 kf0 = *reinterpret_cast<const bf16x8*>(&ks[(nt * 16 + r16) * ALD + koff]);
                    const bf16x8 kf1 = *reinterpret_cast<const bf16x8*>(&ks[(nt * 16 + r16) * ALD + 32 + koff]);
                    floatx4 c = fzero4();
                    c = __builtin_amdgcn_mfma_f32_16x16x32_bf16(kf0, qf0, c, 0, 0, 0);
                    c = __builtin_amdgcn_mfma_f32_16x16x32_bf16(kf1, qf1, c, 0, 0, 0);
                    const ushort4 bb = w ? (ab ? b11 : b10) : (ab ? b01 : b00);
                    const int kbase = kb + w * 32 + ab * 4 + g8;
                    float sc0 = c[0] * SCL2 + bf2f(bb.x);
                    float sc1 = c[1] * SCL2 + bf2f(bb.y);
                    float sc2 = c[2] * SCL2 + bf2f(bb.z);
                    float sc3 = c[3] * SCL2 + bf2f(bb.w);
                    if (kt == v) {                     // causal on diagonal tile only
                        if (kbase + 0 > qcol) sc0 = MNEG;
                        if (kbase + 1 > qcol) sc1 = MNEG;
                        if (kbase + 2 > qcol) sc2 = MNEG;
                        if (kbase + 3 > qcol) sc3 = MNEG;
                    }
                    p[ab][0] = exp2f(sc0);
                    p[ab][1] = exp2f(sc1);
                    p[ab][2] = exp2f(sc2);
                    p[ab][3] = exp2f(sc3);
                }
                // pack P fragment: keys w*32 + 8g + {0..7} in order
                const unsigned int u0 = cvtpk_bf16(p[0][0], p[0][1]);
                const unsigned int u1 = cvtpk_bf16(p[0][2], p[0][3]);
                const unsigned int u2 = cvtpk_bf16(p[1][0], p[1][1]);
                const unsigned int u3 = cvtpk_bf16(p[1][2], p[1][3]);
                Lp += (bfsum2(u0) + bfsum2(u1)) + (bfsum2(u2) + bfsum2(u3));
                union { uint4 u; bf16x8 v; } pf;
                pf.u.x = u0; pf.u.y = u1; pf.u.z = u2; pf.u.w = u3;
                // PV: O^T += V^T · P^T (V natural key order, contiguous reads)
                #pragma unroll
                for (int db = 0; db < 4; db++) {
                    const bf16x8 vf = *reinterpret_cast<const bf16x8*>(&vs[(db * 16 + r16) * ALD + w * 32 + koff]);
                    Ot[db] = __builtin_amdgcn_mfma_f32_16x16x32_bf16(vf, pf.v, Ot[db], 0, 0, 0);
                }
            }
        }
    }
#undef PREFETCH_MACRO
#undef PF_TILE

    // epilogue: complete the row sum across the 4 key-quad lane groups, then scale + store O^T
    float lsum = Lp;
    lsum += __shfl_xor(lsum, 16, 64);
    lsum += __shfl_xor(lsum, 32, 64);
    const float rl = 1.f / lsum;
    const int r4 = (lane >> 4) * 4;
    #pragma unroll
    for (int db = 0; db < 4; db++) {
        ushort4 o;
        o.x = f2bf_rn(Ot[db][0] * rl);
        o.y = f2bf_rn(Ot[db][1] * rl);
        o.z = f2bf_rn(Ot[db][2] * rl);
        o.w = f2bf_rn(Ot[db][3] * rl);
        *reinterpret_cast<ushort4*>(&ctx[((size_t)b * S_ + qcol) * H_ + h * HD_ + db * 16 + r4]) = o;
    }
}

// ---------------------------------------------------------------- launch
extern "C" void kernel_launch(void* const* d_in, const int* in_sizes, int n_in,
                              void* d_out, int out_size, void* d_ws, size_t ws_size,
                              hipStream_t stream) {
    const float* x     = (const float*)d_in[0];
    const int*   mask  = (const int*)d_in[1];
    const float* normw = (const float*)d_in[2];
    const float* normb = (const float*)d_in[3];
    const float* qkvw  = (const float*)d_in[4];
    const float* qkvb  = (const float*)d_in[5];
    const float* ow    = (const float*)d_in[6];
    const float* ob    = (const float*)d_in[7];
    float* out = (float*)d_out;

    char* ws = (char*)d_ws;
    unsigned short* xn_bf   = (unsigned short*)(ws);                      //  8 MB
    unsigned short* qkvwT   = (unsigned short*)(ws + (8ull  << 20));      //  6 MB
    unsigned short* owT     = (unsigned short*)(ws + (14ull << 20));      //  2 MB
    unsigned short* Qb      = (unsigned short*)(ws + (16ull << 20));      //  8 MB [bh][s][d]
    unsigned short* Kb      = (unsigned short*)(ws + (24ull << 20));      //  8 MB [bh][s][d]
    unsigned short* Vtb     = (unsigned short*)(ws + (32ull << 20));      //  8 MB [bh][d][s]
    unsigned short* ctx_bf  = (unsigned short*)(ws + (40ull << 20));      //  8 MB

    cvt_both_k<<<1024, 256, 0, stream>>>(qkvw, ow, qkvwT, owT);
    layernorm_k<<<T_, 256, 0, stream>>>(x, normw, normb, xn_bf);
    gemm_qkv_k<<<dim3(H3_ / BN, T_ / BM), 256, 0, stream>>>(xn_bf, qkvwT, qkvb, Qb, Kb, Vtb);
    attn_k<<<1024, 256, 0, stream>>>(Qb, Kb, Vtb, mask, ctx_bf);
    gemm_proj_k<<<dim3(H_ / BN, T_ / BM), 256, 0, stream>>>(ctx_bf, owT, ob, out, T_, H_, H_);
}

// Round 7
// 190.978 us; speedup vs baseline: 1.0954x; 1.0328x over previous
//
#include <hip/hip_runtime.h>
#include <hip/hip_bf16.h>

#define B_  2
#define S_  2048
#define H_  1024
#define NH_ 16
#define HD_ 64
#define T_  (B_*S_)     // 4096 tokens
#define H3_ (3*H_)      // 3072

typedef float  floatx4 __attribute__((ext_vector_type(4)));
typedef __bf16 bf16x8  __attribute__((ext_vector_type(8)));

__device__ inline unsigned short f2bf_rn(float f) {
    union { float f; unsigned int u; } v; v.f = f;
    unsigned int u = v.u;
    u += 0x7fffu + ((u >> 16) & 1u);
    return (unsigned short)(u >> 16);
}
__device__ inline floatx4 fzero4() { floatx4 v; v[0]=0.f; v[1]=0.f; v[2]=0.f; v[3]=0.f; return v; }

__device__ inline float bf2f(unsigned short u) {
    union { unsigned int i; float f; } x; x.i = ((unsigned int)u) << 16; return x.f;
}

// pack two f32 -> one u32 of two bf16 (lo = src0), RNE; no builtin on gfx950 -> inline asm
__device__ inline unsigned int cvtpk_bf16(float lo, float hi) {
    unsigned int r;
    asm("v_cvt_pk_bf16_f32 %0, %1, %2" : "=v"(r) : "v"(lo), "v"(hi));
    return r;
}

// async global->LDS, 16B per lane; LDS dest = wave-uniform base + lane*16
__device__ inline void gload_lds16(const unsigned short* g, unsigned short* l) {
    __builtin_amdgcn_global_load_lds((const __attribute__((address_space(1))) unsigned int*)g,
                                     (__attribute__((address_space(3))) unsigned int*)l,
                                     16, 0, 0);
}

// ---------------------------------------------------------------- fused cast + transpose (both weights, one launch)
#define TLD 72
__global__ __launch_bounds__(256) void cvt_both_k(const float* __restrict__ qkvw,
                                                  const float* __restrict__ ow,
                                                  unsigned short* __restrict__ qkvwT,
                                                  unsigned short* __restrict__ owT) {
    __shared__ unsigned short Ts[64 * TLD];
    int id = blockIdx.x;
    const float* W; unsigned short* Wt; int N, nb, kb;
    if (id < 768) { W = qkvw; Wt = qkvwT; N = H3_; nb = (id % 48) * 64; kb = (id / 48) * 64; }
    else { id -= 768; W = ow; Wt = owT; N = H_; nb = (id % 16) * 64; kb = (id / 16) * 64; }
    const int K = H_;
    const int tid = threadIdx.x;
    #pragma unroll
    for (int p = 0; p < 4; p++) {
        const int krow = kb + p * 16 + (tid >> 4);
        const int ncol = (tid & 15) * 4;
        const float4 w = *reinterpret_cast<const float4*>(&W[(size_t)krow * N + nb + ncol]);
        Ts[(ncol + 0) * TLD + p * 16 + (tid >> 4)] = f2bf_rn(w.x);
        Ts[(ncol + 1) * TLD + p * 16 + (tid >> 4)] = f2bf_rn(w.y);
        Ts[(ncol + 2) * TLD + p * 16 + (tid >> 4)] = f2bf_rn(w.z);
        Ts[(ncol + 3) * TLD + p * 16 + (tid >> 4)] = f2bf_rn(w.w);
    }
    __syncthreads();
    #pragma unroll
    for (int p = 0; p < 2; p++) {
        const int n = (tid >> 3) + p * 32;
        const int k8 = (tid & 7) * 8;
        const uint4 v = *reinterpret_cast<const uint4*>(&Ts[n * TLD + k8]);
        *reinterpret_cast<uint4*>(&Wt[(size_t)(nb + n) * K + kb + k8]) = v;
    }
}

// ---------------------------------------------------------------- LayerNorm (fp32 stats, bf16 out)
__global__ __launch_bounds__(256) void layernorm_k(const float* __restrict__ x,
                                                   const float* __restrict__ w,
                                                   const float* __restrict__ b,
                                                   unsigned short* __restrict__ xn) {
    const int t   = blockIdx.x;
    const int tid = threadIdx.x;
    const float4 v = reinterpret_cast<const float4*>(x + (size_t)t * H_)[tid];
    float s  = v.x + v.y + v.z + v.w;
    float s2 = v.x*v.x + v.y*v.y + v.z*v.z + v.w*v.w;
    for (int off = 32; off > 0; off >>= 1) {
        s  += __shfl_down(s,  off, 64);
        s2 += __shfl_down(s2, off, 64);
    }
    __shared__ float red[8];
    const int wave = tid >> 6, lane = tid & 63;
    if (lane == 0) { red[wave] = s; red[4 + wave] = s2; }
    __syncthreads();
    if (tid == 0) {
        red[0] = red[0] + red[1] + red[2] + red[3];
        red[4] = red[4] + red[5] + red[6] + red[7];
    }
    __syncthreads();
    const float mean = red[0] * (1.f / H_);
    const float var  = red[4] * (1.f / H_) - mean * mean;
    const float rstd = rsqrtf(var + 1e-5f);
    const float4 wv = reinterpret_cast<const float4*>(w)[tid];
    const float4 bv = reinterpret_cast<const float4*>(b)[tid];
    ushort4 o = make_ushort4(f2bf_rn((v.x - mean) * rstd * wv.x + bv.x),
                             f2bf_rn((v.y - mean) * rstd * wv.y + bv.y),
                             f2bf_rn((v.z - mean) * rstd * wv.z + bv.z),
                             f2bf_rn((v.w - mean) * rstd * wv.w + bv.w));
    reinterpret_cast<ushort4*>(xn + (size_t)t * H_)[tid] = o;
}

// ---------------------------------------------------------------- shared GEMM core: BK=64 as two BK=32 sub-buffers
#define BM 128
#define BN 128

__device__ inline void gemm_core(const unsigned short* __restrict__ A,
                                 const unsigned short* __restrict__ Bt,
                                 int K, int mBase, int nBase,
                                 int tid, floatx4 acc[4][4],
                                 unsigned short* As0, unsigned short* As1,
                                 unsigned short* Bs0, unsigned short* Bs1) {
    const int lane = tid & 63;
    const int wave = tid >> 6;
    const int wr = wave >> 1, wc = wave & 1;
    const int srow = lane >> 2;        // 0..15
    const int scol = (lane & 3) * 8;   // 0,8,16,24
    const int mrow = lane & 15;
    const int koff = (lane >> 4) * 8;

    for (int kb = 0; kb < K; kb += 64) {
        __syncthreads();
        #pragma unroll
        for (int p = 0; p < 2; p++) {
            const int r = wave * 16 + p * 64;
            const size_t ga = (size_t)(mBase + r + srow) * K + kb + scol;
            const size_t gb = (size_t)(nBase + r + srow) * K + kb + scol;
            gload_lds16(&A [ga],      &As0[r * 32]);
            gload_lds16(&A [ga + 32], &As1[r * 32]);
            gload_lds16(&Bt[gb],      &Bs0[r * 32]);
            gload_lds16(&Bt[gb + 32], &Bs1[r * 32]);
        }
        __syncthreads();

        #pragma unroll
        for (int half = 0; half < 2; half++) {
            const unsigned short* As = half ? As1 : As0;
            const unsigned short* Bs = half ? Bs1 : Bs0;
            bf16x8 afrag[4], bfrag[4];
            #pragma unroll
            for (int mt = 0; mt < 4; mt++)
                afrag[mt] = *reinterpret_cast<const bf16x8*>(&As[(wr * 64 + mt * 16 + mrow) * 32 + koff]);
            #pragma unroll
            for (int nt = 0; nt < 4; nt++)
                bfrag[nt] = *reinterpret_cast<const bf16x8*>(&Bs[(wc * 64 + nt * 16 + mrow) * 32 + koff]);
            #pragma unroll
            for (int mt = 0; mt < 4; mt++)
                #pragma unroll
                for (int nt = 0; nt < 4; nt++)
                    acc[mt][nt] = __builtin_amdgcn_mfma_f32_16x16x32_bf16(afrag[mt], bfrag[nt], acc[mt][nt], 0, 0, 0);
        }
    }
}

// ---------------------------------------------------------------- QKV GEMM with fused bias+rotary+V-transpose epilogue
__global__ __launch_bounds__(256) void gemm_qkv_k(const unsigned short* __restrict__ A,
                                                  const unsigned short* __restrict__ Bt,
                                                  const float* __restrict__ bias,
                                                  unsigned short* __restrict__ Qo,
                                                  unsigned short* __restrict__ Ko,
                                                  unsigned short* __restrict__ Vto) {
    __shared__ unsigned short As0[BM * 32], As1[BM * 32];
    __shared__ unsigned short Bs0[BN * 32], Bs1[BN * 32];

    const int tid  = threadIdx.x;
    const int lane = tid & 63;
    const int wave = tid >> 6;
    const int wr = wave >> 1, wc = wave & 1;
    const int mBase = blockIdx.y * BM;
    const int nBase = blockIdx.x * BN;

    floatx4 acc[4][4];
    #pragma unroll
    for (int i = 0; i < 4; i++)
        #pragma unroll
        for (int j = 0; j < 4; j++) acc[i][j] = fzero4();

    gemm_core(A, Bt, H_, mBase, nBase, tid, acc, As0, As1, Bs0, Bs1);

    const int col0 = lane & 15;
    const int r0   = (lane >> 4) * 4;
    const int hg   = (nBase + wc * 64) >> 6;   // global head index (wave-uniform)
    const int sec  = hg >> 4;                  // 0=q 1=k 2=v
    const int h    = hg & 15;

    float bs[4];
    #pragma unroll
    for (int nt = 0; nt < 4; nt++) bs[nt] = bias[nBase + wc * 64 + nt * 16 + col0];

    if (sec < 2) {
        unsigned short* dst = (sec == 0) ? Qo : Ko;
        const float if0 = __expf((float)col0        * (-0.2878231366f));   // j = col0
        const float if1 = __expf((float)(16 + col0) * (-0.2878231366f));   // j = 16+col0
        #pragma unroll
        for (int mt = 0; mt < 4; mt++) {
            #pragma unroll
            for (int reg = 0; reg < 4; reg++) {
                const int t  = mBase + wr * 64 + mt * 16 + r0 + reg;
                const int bb = t >> 11;
                const int s  = t & (S_ - 1);
                float sn0, cs0, sn1, cs1;
                __sincosf((float)s * if0, &sn0, &cs0);
                __sincosf((float)s * if1, &sn1, &cs1);
                const float v0 = acc[mt][0][reg] + bs[0];   // d = col0
                const float v1 = acc[mt][1][reg] + bs[1];   // d = 16+col0
                const float v2 = acc[mt][2][reg] + bs[2];   // d = 32+col0
                const float v3 = acc[mt][3][reg] + bs[3];   // d = 48+col0
                const float o0 = v0 * cs0 - v2 * sn0;
                const float o1 = v1 * cs1 - v3 * sn1;
                const float o2 = v2 * cs0 + v0 * sn0;
                const float o3 = v3 * cs1 + v1 * sn1;
                const size_t rb = ((size_t)(bb * NH_ + h) * S_ + s) * HD_;
                dst[rb +      col0] = f2bf_rn(o0);
                dst[rb + 16 + col0] = f2bf_rn(o1);
                dst[rb + 32 + col0] = f2bf_rn(o2);
                dst[rb + 48 + col0] = f2bf_rn(o3);
            }
        }
    } else {
        #pragma unroll
        for (int mt = 0; mt < 4; mt++) {
            const int t0 = mBase + wr * 64 + mt * 16 + r0;   // 4 consecutive tokens, 4-aligned
            const int bb = t0 >> 11;
            const int s0 = t0 & (S_ - 1);
            #pragma unroll
            for (int nt = 0; nt < 4; nt++) {
                const int d = nt * 16 + col0;
                ushort4 o;
                o.x = f2bf_rn(acc[mt][nt][0] + bs[nt]);
                o.y = f2bf_rn(acc[mt][nt][1] + bs[nt]);
                o.z = f2bf_rn(acc[mt][nt][2] + bs[nt]);
                o.w = f2bf_rn(acc[mt][nt][3] + bs[nt]);
                *reinterpret_cast<ushort4*>(&Vto[((size_t)(bb * NH_ + h) * HD_ + d) * S_ + s0]) = o;
            }
        }
    }
}

// ---------------------------------------------------------------- proj GEMM: 128x64 tiles -> 512 blocks, 2 blocks/CU
// (old 128x128 grid was 256 blocks = 1 block/CU, 4 waves/CU — occupancy-starved). Each wave owns a
// 32x64 sub-tile (acc[2][4]). LDS 24.5KB.
__global__ __launch_bounds__(256) void gemm_proj_k(const unsigned short* __restrict__ A,
                                                   const unsigned short* __restrict__ Bt,
                                                   const float* __restrict__ bias,
                                                   float* __restrict__ Cf,
                                                   int M, int N, int K) {
    __shared__ unsigned short As0[128 * 32], As1[128 * 32];
    __shared__ unsigned short Bs0[ 64 * 32], Bs1[ 64 * 32];

    const int tid  = threadIdx.x;
    const int lane = tid & 63;
    const int wave = tid >> 6;              // 0..3, owns rows wave*32..+31
    const int mBase = blockIdx.y * 128;
    const int nBase = blockIdx.x * 64;

    const int srow = lane >> 2;             // 0..15
    const int scol = (lane & 3) * 8;        // 0,8,16,24
    const int mrow = lane & 15;
    const int koff = (lane >> 4) * 8;

    floatx4 acc[2][4];
    #pragma unroll
    for (int i = 0; i < 2; i++)
        #pragma unroll
        for (int j = 0; j < 4; j++) acc[i][j] = fzero4();

    for (int kb = 0; kb < K; kb += 64) {
        __syncthreads();
        #pragma unroll
        for (int p = 0; p < 2; p++) {
            const int r = wave * 16 + p * 64;
            const size_t ga = (size_t)(mBase + r + srow) * K + kb + scol;
            gload_lds16(&A[ga],      &As0[r * 32]);
            gload_lds16(&A[ga + 32], &As1[r * 32]);
        }
        {
            const int r = wave * 16;
            const size_t gb = (size_t)(nBase + r + srow) * K + kb + scol;
            gload_lds16(&Bt[gb],      &Bs0[r * 32]);
            gload_lds16(&Bt[gb + 32], &Bs1[r * 32]);
        }
        __syncthreads();

        #pragma unroll
        for (int half = 0; half < 2; half++) {
            const unsigned short* As = half ? As1 : As0;
            const unsigned short* Bs = half ? Bs1 : Bs0;
            bf16x8 afrag[2], bfrag[4];
            #pragma unroll
            for (int mt = 0; mt < 2; mt++)
                afrag[mt] = *reinterpret_cast<const bf16x8*>(&As[(wave * 32 + mt * 16 + mrow) * 32 + koff]);
            #pragma unroll
            for (int nt = 0; nt < 4; nt++)
                bfrag[nt] = *reinterpret_cast<const bf16x8*>(&Bs[(nt * 16 + mrow) * 32 + koff]);
            #pragma unroll
            for (int mt = 0; mt < 2; mt++)
                #pragma unroll
                for (int nt = 0; nt < 4; nt++)
                    acc[mt][nt] = __builtin_amdgcn_mfma_f32_16x16x32_bf16(afrag[mt], bfrag[nt], acc[mt][nt], 0, 0, 0);
        }
    }

    const int col0 = lane & 15;
    const int r0   = (lane >> 4) * 4;
    #pragma unroll
    for (int mt = 0; mt < 2; mt++) {
        #pragma unroll
        for (int nt = 0; nt < 4; nt++) {
            const int gcol = nBase + nt * 16 + col0;
            const float bsv = bias[gcol];
            #pragma unroll
            for (int reg = 0; reg < 4; reg++) {
                const int grow = mBase + wave * 32 + mt * 16 + r0 + reg;
                Cf[(size_t)grow * N + gcol] = acc[mt][nt][reg] + bsv;
            }
        }
    }
}

// ---------------------------------------------------------------- flash attention: in-register P + LDS mask-bias table
// r6 structure (swapped QK, key-permuted K staging, in-register P via cvt_pk, LDS bias table) plus:
// (1) denominator via ones-A MFMA — one mfma(ones, P) per 32-key window accumulates the full column
//     sum into every output row (kills the bfsum chain ~16 VALU/tile + 2 epilogue shuffles; MFMA pipe
//     is 13.5% busy, free capacity); (2) s_setprio(1) around the PV MFMA cluster (m191: +4-7% attn).
#define ALD 72
#define SCL2 0.1803368801f      /* 0.125 * log2(e) */
#define MNEG -14427.0f          /* -10000 * log2(e), causal fill */

__global__ __launch_bounds__(256, 4) void attn_k(const unsigned short* __restrict__ Q,
                                                 const unsigned short* __restrict__ Kg,
                                                 const unsigned short* __restrict__ Vt,
                                                 const int* __restrict__ mask,
                                                 unsigned short* __restrict__ ctx) {
    const int id = blockIdx.x;              // 0..1023
    const int bh = id & 31;                 // id%8 fixed per bh -> XCD locality
    const int v  = 31 - (id >> 5);          // q-tile index; most work first
    const int b  = bh >> 4;
    const int h  = bh & 15;
    const int tid  = threadIdx.x;
    const int lane = tid & 63;
    const int wave = tid >> 6;

    __shared__ unsigned short Ks [2][64 * ALD];   // 18.4 KB (key-permuted rows)
    __shared__ unsigned short Vts[2][64 * ALD];   // 18.4 KB (natural key order)
    __shared__ unsigned short Mb [S_];            //  4.0 KB bf16 mask-bias per key

    const size_t base = (size_t)bh * S_ * HD_;
    const int qbase = v * 64 + wave * 16;
    const int r16  = lane & 15;             // A-row / output-col lane index
    const int koff = (lane >> 4) * 8;       // d-offset in fragments / key-offset in PV reads
    const int g8   = (lane >> 4) * 8;       // key-group base for St quads
    const int qcol = qbase + r16;           // this lane's q row (output column)

    // ---- mask-bias table: 8 keys per thread, one b128 store; visible after first barrier
    {
        const int k0 = tid * 8;
        const int4 ma = *reinterpret_cast<const int4*>(&mask[b * S_ + k0]);
        const int4 mc = *reinterpret_cast<const int4*>(&mask[b * S_ + k0 + 4]);
        union { unsigned short us[8]; uint4 q; } pk;
        pk.us[0] = f2bf_rn((1.f - (float)ma.x) * MNEG);
        pk.us[1] = f2bf_rn((1.f - (float)ma.y) * MNEG);
        pk.us[2] = f2bf_rn((1.f - (float)ma.z) * MNEG);
        pk.us[3] = f2bf_rn((1.f - (float)ma.w) * MNEG);
        pk.us[4] = f2bf_rn((1.f - (float)mc.x) * MNEG);
        pk.us[5] = f2bf_rn((1.f - (float)mc.y) * MNEG);
        pk.us[6] = f2bf_rn((1.f - (float)mc.z) * MNEG);
        pk.us[7] = f2bf_rn((1.f - (float)mc.w) * MNEG);
        *reinterpret_cast<uint4*>(&Mb[k0]) = pk.q;
    }

    const bf16x8 qf0 = *reinterpret_cast<const bf16x8*>(&Q[base + (size_t)(qbase + r16) * HD_ + koff]);
    const bf16x8 qf1 = *reinterpret_cast<const bf16x8*>(&Q[base + (size_t)(qbase + r16) * HD_ + 32 + koff]);

    bf16x8 onesA;
    #pragma unroll
    for (int q = 0; q < 8; q++) onesA[q] = (__bf16)1.f;

    floatx4 Ot[4];                           // O^T: lane holds O^T[d=db*16+(lane>>4)*4+reg][q=qcol]
    #pragma unroll
    for (int db = 0; db < 4; db++) Ot[db] = fzero4();
    floatx4 Lacc = fzero4();                 // every row = column sum of P (ones-A MFMA)

    const int srow = tid >> 3;          // 0..31
    const int scol = (tid & 7) * 8;
    // key permutation within a 32-window: row r holds key pi(r)
    const int pi = ((srow & 12) << 1) | (srow & 3) | (((srow >> 4) & 1) << 2);

    // named prefetch registers for 2 tiles (no runtime-indexed arrays -> no scratch)
    uint4 k00, k01, k10, k11, v00, v01, v10, v11;
#define PF_TILE(TT, KR0, KR1, VR0, VR1) do {                                                   \
        const int kb_ = (TT) * 64;                                                             \
        KR0 = *reinterpret_cast<const uint4*>(&Kg[base + (size_t)(kb_ + pi)      * HD_ + scol]); \
        KR1 = *reinterpret_cast<const uint4*>(&Kg[base + (size_t)(kb_ + 32 + pi) * HD_ + scol]); \
        VR0 = *reinterpret_cast<const uint4*>(&Vt[base + (size_t)srow        * S_ + kb_ + scol]);  \
        VR1 = *reinterpret_cast<const uint4*>(&Vt[base + (size_t)(srow + 32) * S_ + kb_ + scol]);  \
    } while (0)
#define PREFETCH_MACRO(MI) do {                                                                \
        const int t0_ = min(2 * (MI), v);                                                      \
        const int t1_ = min(2 * (MI) + 1, v);                                                  \
        PF_TILE(t0_, k00, k01, v00, v01);                                                      \
        PF_TILE(t1_, k10, k11, v10, v11);                                                      \
    } while (0)

    const int nmac = (v + 2) >> 1;
    PREFETCH_MACRO(0);

    for (int mi = 0; mi < nmac; mi++) {
        if (mi) __syncthreads();                       // WAR: prior macro's LDS reads done
        *reinterpret_cast<uint4*>(&Ks [0][ srow       * ALD + scol]) = k00;
        *reinterpret_cast<uint4*>(&Ks [0][(srow + 32) * ALD + scol]) = k01;
        *reinterpret_cast<uint4*>(&Ks [1][ srow       * ALD + scol]) = k10;
        *reinterpret_cast<uint4*>(&Ks [1][(srow + 32) * ALD + scol]) = k11;
        *reinterpret_cast<uint4*>(&Vts[0][ srow       * ALD + scol]) = v00;
        *reinterpret_cast<uint4*>(&Vts[0][(srow + 32) * ALD + scol]) = v01;
        *reinterpret_cast<uint4*>(&Vts[1][ srow       * ALD + scol]) = v10;
        *reinterpret_cast<uint4*>(&Vts[1][(srow + 32) * ALD + scol]) = v11;
        __syncthreads();                               // staged tiles + (mi==0) Mb table visible
        if (mi + 1 < nmac) PREFETCH_MACRO(mi + 1);

        #pragma unroll
        for (int half = 0; half < 2; half++) {
            const int kt = 2 * mi + half;
            if (half && kt > v) continue;              // wave-uniform skip (odd tile count)
            const int kb = kt * 64;
            const unsigned short* ks = Ks [half];
            const unsigned short* vs = Vts[half];

            // ---- per-tile bias: four 8B broadcast LDS reads, latency hidden under QK
            const unsigned short* mbp = &Mb[kb + g8];
            const ushort4 b00 = *reinterpret_cast<const ushort4*>(mbp);        // w0 ab0
            const ushort4 b01 = *reinterpret_cast<const ushort4*>(mbp + 4);    // w0 ab1
            const ushort4 b10 = *reinterpret_cast<const ushort4*>(mbp + 32);   // w1 ab0
            const ushort4 b11 = *reinterpret_cast<const ushort4*>(mbp + 36);   // w1 ab1

            #pragma unroll
            for (int w = 0; w < 2; w++) {              // two 32-key windows
                float p[2][4];
                #pragma unroll
                for (int ab = 0; ab < 2; ab++) {
                    const int nt = w * 2 + ab;
                    // St = K·Q^T over permuted K rows; quad reg -> key kb + w*32 + ab*4 + 8g + reg
                    const bf16x8 kf0 = *reinterpret_cast<const bf16x8*>(&ks[(nt * 16 + r16) * ALD + koff]);
                    const bf16x8 kf1 = *reinterpret_cast<const bf16x8*>(&ks[(nt * 16 + r16) * ALD + 32 + koff]);
                    floatx4 c = fzero4();
                    c = __builtin_amdgcn_mfma_f32_16x16x32_bf16(kf0, qf0, c, 0, 0, 0);
                    c = __builtin_amdgcn_mfma_f32_16x16x32_bf16(kf1, qf1, c, 0, 0, 0);
                    const ushort4 bb = w ? (ab ? b11 : b10) : (ab ? b01 : b00);
                    const int kbase = kb + w * 32 + ab * 4 + g8;
                    float sc0 = c[0] * SCL2 + bf2f(bb.x);
                    float sc1 = c[1] * SCL2 + bf2f(bb.y);
                    float sc2 = c[2] * SCL2 + bf2f(bb.z);
                    float sc3 = c[3] * SCL2 + bf2f(bb.w);
                    if (kt == v) {                     // causal on diagonal tile only
                        if (kbase + 0 > qcol) sc0 = MNEG;
                        if (kbase + 1 > qcol) sc1 = MNEG;
                        if (kbase + 2 > qcol) sc2 = MNEG;
                        if (kbase + 3 > qcol) sc3 = MNEG;
                    }
                    p[ab][0] = exp2f(sc0);
                    p[ab][1] = exp2f(sc1);
                    p[ab][2] = exp2f(sc2);
                    p[ab][3] = exp2f(sc3);
                }
                // pack P fragment: keys w*32 + 8g + {0..7} in order
                union { uint4 u; bf16x8 v; } pf;
                pf.u.x = cvtpk_bf16(p[0][0], p[0][1]);
                pf.u.y = cvtpk_bf16(p[0][2], p[0][3]);
                pf.u.z = cvtpk_bf16(p[1][0], p[1][1]);
                pf.u.w = cvtpk_bf16(p[1][2], p[1][3]);
                // PV: O^T += V^T · P^T (V natural key order, contiguous reads); L via ones-A MFMA
                __builtin_amdgcn_s_setprio(1);
                #pragma unroll
                for (int db = 0; db < 4; db++) {
                    const bf16x8 vf = *reinterpret_cast<const bf16x8*>(&vs[(db * 16 + r16) * ALD + w * 32 + koff]);
                    Ot[db] = __builtin_amdgcn_mfma_f32_16x16x32_bf16(vf, pf.v, Ot[db], 0, 0, 0);
                }
                Lacc = __builtin_amdgcn_mfma_f32_16x16x32_bf16(onesA, pf.v, Lacc, 0, 0, 0);
                __builtin_amdgcn_s_setprio(0);
            }
        }
    }
#undef PREFETCH_MACRO
#undef PF_TILE

    // epilogue: Lacc rows all equal the full column sum — no cross-lane reduce needed
    const float rl = 1.f / Lacc[0];
    const int r4 = (lane >> 4) * 4;
    #pragma unroll
    for (int db = 0; db < 4; db++) {
        ushort4 o;
        o.x = f2bf_rn(Ot[db][0] * rl);
        o.y = f2bf_rn(Ot[db][1] * rl);
        o.z = f2bf_rn(Ot[db][2] * rl);
        o.w = f2bf_rn(Ot[db][3] * rl);
        *reinterpret_cast<ushort4*>(&ctx[((size_t)b * S_ + qcol) * H_ + h * HD_ + db * 16 + r4]) = o;
    }
}

// ---------------------------------------------------------------- launch
extern "C" void kernel_launch(void* const* d_in, const int* in_sizes, int n_in,
                              void* d_out, int out_size, void* d_ws, size_t ws_size,
                              hipStream_t stream) {
    const float* x     = (const float*)d_in[0];
    const int*   mask  = (const int*)d_in[1];
    const float* normw = (const float*)d_in[2];
    const float* normb = (const float*)d_in[3];
    const float* qkvw  = (const float*)d_in[4];
    const float* qkvb  = (const float*)d_in[5];
    const float* ow    = (const float*)d_in[6];
    const float* ob    = (const float*)d_in[7];
    float* out = (float*)d_out;

    char* ws = (char*)d_ws;
    unsigned short* xn_bf   = (unsigned short*)(ws);                      //  8 MB
    unsigned short* qkvwT   = (unsigned short*)(ws + (8ull  << 20));      //  6 MB
    unsigned short* owT     = (unsigned short*)(ws + (14ull << 20));      //  2 MB
    unsigned short* Qb      = (unsigned short*)(ws + (16ull << 20));      //  8 MB [bh][s][d]
    unsigned short* Kb      = (unsigned short*)(ws + (24ull << 20));      //  8 MB [bh][s][d]
    unsigned short* Vtb     = (unsigned short*)(ws + (32ull << 20));      //  8 MB [bh][d][s]
    unsigned short* ctx_bf  = (unsigned short*)(ws + (40ull << 20));      //  8 MB

    cvt_both_k<<<1024, 256, 0, stream>>>(qkvw, ow, qkvwT, owT);
    layernorm_k<<<T_, 256, 0, stream>>>(x, normw, normb, xn_bf);
    gemm_qkv_k<<<dim3(H3_ / BN, T_ / BM), 256, 0, stream>>>(xn_bf, qkvwT, qkvb, Qb, Kb, Vtb);
    attn_k<<<1024, 256, 0, stream>>>(Qb, Kb, Vtb, mask, ctx_bf);
    gemm_proj_k<<<dim3(H_ / 64, T_ / 128), 256, 0, stream>>>(ctx_bf, owT, ob, out, T_, H_, H_);
}

// Round 8
// 190.118 us; speedup vs baseline: 1.1004x; 1.0045x over previous
//
#include <hip/hip_runtime.h>
#include <hip/hip_bf16.h>

#define B_  2
#define S_  2048
#define H_  1024
#define NH_ 16
#define HD_ 64
#define T_  (B_*S_)     // 4096 tokens
#define H3_ (3*H_)      // 3072

typedef float  floatx4 __attribute__((ext_vector_type(4)));
typedef __bf16 bf16x8  __attribute__((ext_vector_type(8)));

__device__ inline unsigned short f2bf_rn(float f) {
    union { float f; unsigned int u; } v; v.f = f;
    unsigned int u = v.u;
    u += 0x7fffu + ((u >> 16) & 1u);
    return (unsigned short)(u >> 16);
}
__device__ inline floatx4 fzero4() { floatx4 v; v[0]=0.f; v[1]=0.f; v[2]=0.f; v[3]=0.f; return v; }

__device__ inline float bf2f(unsigned short u) {
    union { unsigned int i; float f; } x; x.i = ((unsigned int)u) << 16; return x.f;
}

// pack two f32 -> one u32 of two bf16 (lo = src0), RNE; no builtin on gfx950 -> inline asm
__device__ inline unsigned int cvtpk_bf16(float lo, float hi) {
    unsigned int r;
    asm("v_cvt_pk_bf16_f32 %0, %1, %2" : "=v"(r) : "v"(lo), "v"(hi));
    return r;
}

// async global->LDS, 16B per lane; LDS dest = wave-uniform base + lane*16
__device__ inline void gload_lds16(const unsigned short* g, unsigned short* l) {
    __builtin_amdgcn_global_load_lds((const __attribute__((address_space(1))) unsigned int*)g,
                                     (__attribute__((address_space(3))) unsigned int*)l,
                                     16, 0, 0);
}

// ---------------------------------------------------------------- fused preprocessing: weight cast+transpose AND LayerNorm
// blocks 0..1023: cvt (768 qkvw tiles + 256 ow tiles); blocks 1024..5119: LN (one token each).
// Independent memory streams (weights vs activations) -> overlap; saves one launch gap.
#define TLD 72
__global__ __launch_bounds__(256) void pre_k(const float* __restrict__ qkvw,
                                             const float* __restrict__ ow,
                                             unsigned short* __restrict__ qkvwT,
                                             unsigned short* __restrict__ owT,
                                             const float* __restrict__ x,
                                             const float* __restrict__ nw,
                                             const float* __restrict__ nb,
                                             unsigned short* __restrict__ xn) {
    const int tid = threadIdx.x;
    if (blockIdx.x < 1024) {
        __shared__ unsigned short Ts[64 * TLD];
        int id = blockIdx.x;
        const float* W; unsigned short* Wt; int N, nbs, kb;
        if (id < 768) { W = qkvw; Wt = qkvwT; N = H3_; nbs = (id % 48) * 64; kb = (id / 48) * 64; }
        else { id -= 768; W = ow; Wt = owT; N = H_; nbs = (id % 16) * 64; kb = (id / 16) * 64; }
        const int K = H_;
        #pragma unroll
        for (int p = 0; p < 4; p++) {
            const int krow = kb + p * 16 + (tid >> 4);
            const int ncol = (tid & 15) * 4;
            const float4 w = *reinterpret_cast<const float4*>(&W[(size_t)krow * N + nbs + ncol]);
            Ts[(ncol + 0) * TLD + p * 16 + (tid >> 4)] = f2bf_rn(w.x);
            Ts[(ncol + 1) * TLD + p * 16 + (tid >> 4)] = f2bf_rn(w.y);
            Ts[(ncol + 2) * TLD + p * 16 + (tid >> 4)] = f2bf_rn(w.z);
            Ts[(ncol + 3) * TLD + p * 16 + (tid >> 4)] = f2bf_rn(w.w);
        }
        __syncthreads();
        #pragma unroll
        for (int p = 0; p < 2; p++) {
            const int n = (tid >> 3) + p * 32;
            const int k8 = (tid & 7) * 8;
            const uint4 v = *reinterpret_cast<const uint4*>(&Ts[n * TLD + k8]);
            *reinterpret_cast<uint4*>(&Wt[(size_t)(nbs + n) * K + kb + k8]) = v;
        }
    } else {
        const int t = blockIdx.x - 1024;
        const float4 v = reinterpret_cast<const float4*>(x + (size_t)t * H_)[tid];
        float s  = v.x + v.y + v.z + v.w;
        float s2 = v.x*v.x + v.y*v.y + v.z*v.z + v.w*v.w;
        for (int off = 32; off > 0; off >>= 1) {
            s  += __shfl_down(s,  off, 64);
            s2 += __shfl_down(s2, off, 64);
        }
        __shared__ float red[8];
        const int wave = tid >> 6, lane = tid & 63;
        if (lane == 0) { red[wave] = s; red[4 + wave] = s2; }
        __syncthreads();
        if (tid == 0) {
            red[0] = red[0] + red[1] + red[2] + red[3];
            red[4] = red[4] + red[5] + red[6] + red[7];
        }
        __syncthreads();
        const float mean = red[0] * (1.f / H_);
        const float var  = red[4] * (1.f / H_) - mean * mean;
        const float rstd = rsqrtf(var + 1e-5f);
        const float4 wv = reinterpret_cast<const float4*>(nw)[tid];
        const float4 bv = reinterpret_cast<const float4*>(nb)[tid];
        ushort4 o = make_ushort4(f2bf_rn((v.x - mean) * rstd * wv.x + bv.x),
                                 f2bf_rn((v.y - mean) * rstd * wv.y + bv.y),
                                 f2bf_rn((v.z - mean) * rstd * wv.z + bv.z),
                                 f2bf_rn((v.w - mean) * rstd * wv.w + bv.w));
        reinterpret_cast<ushort4*>(xn + (size_t)t * H_)[tid] = o;
    }
}

// ---------------------------------------------------------------- shared GEMM core: BK=64 as two BK=32 sub-buffers
#define BM 128
#define BN 128

__device__ inline void gemm_core(const unsigned short* __restrict__ A,
                                 const unsigned short* __restrict__ Bt,
                                 int K, int mBase, int nBase,
                                 int tid, floatx4 acc[4][4],
                                 unsigned short* As0, unsigned short* As1,
                                 unsigned short* Bs0, unsigned short* Bs1) {
    const int lane = tid & 63;
    const int wave = tid >> 6;
    const int wr = wave >> 1, wc = wave & 1;
    const int srow = lane >> 2;        // 0..15
    const int scol = (lane & 3) * 8;   // 0,8,16,24
    const int mrow = lane & 15;
    const int koff = (lane >> 4) * 8;

    for (int kb = 0; kb < K; kb += 64) {
        __syncthreads();
        #pragma unroll
        for (int p = 0; p < 2; p++) {
            const int r = wave * 16 + p * 64;
            const size_t ga = (size_t)(mBase + r + srow) * K + kb + scol;
            const size_t gb = (size_t)(nBase + r + srow) * K + kb + scol;
            gload_lds16(&A [ga],      &As0[r * 32]);
            gload_lds16(&A [ga + 32], &As1[r * 32]);
            gload_lds16(&Bt[gb],      &Bs0[r * 32]);
            gload_lds16(&Bt[gb + 32], &Bs1[r * 32]);
        }
        __syncthreads();

        #pragma unroll
        for (int half = 0; half < 2; half++) {
            const unsigned short* As = half ? As1 : As0;
            const unsigned short* Bs = half ? Bs1 : Bs0;
            bf16x8 afrag[4], bfrag[4];
            #pragma unroll
            for (int mt = 0; mt < 4; mt++)
                afrag[mt] = *reinterpret_cast<const bf16x8*>(&As[(wr * 64 + mt * 16 + mrow) * 32 + koff]);
            #pragma unroll
            for (int nt = 0; nt < 4; nt++)
                bfrag[nt] = *reinterpret_cast<const bf16x8*>(&Bs[(wc * 64 + nt * 16 + mrow) * 32 + koff]);
            #pragma unroll
            for (int mt = 0; mt < 4; mt++)
                #pragma unroll
                for (int nt = 0; nt < 4; nt++)
                    acc[mt][nt] = __builtin_amdgcn_mfma_f32_16x16x32_bf16(afrag[mt], bfrag[nt], acc[mt][nt], 0, 0, 0);
        }
    }
}

// ---------------------------------------------------------------- QKV GEMM, 1D grid + XCD swizzle (4 A-panels per XCD)
__global__ __launch_bounds__(256) void gemm_qkv_k(const unsigned short* __restrict__ A,
                                                  const unsigned short* __restrict__ Bt,
                                                  const float* __restrict__ bias,
                                                  unsigned short* __restrict__ Qo,
                                                  unsigned short* __restrict__ Ko,
                                                  unsigned short* __restrict__ Vto) {
    __shared__ unsigned short As0[BM * 32], As1[BM * 32];
    __shared__ unsigned short Bs0[BN * 32], Bs1[BN * 32];

    const int tid  = threadIdx.x;
    const int lane = tid & 63;
    const int wave = tid >> 6;
    const int wr = wave >> 1, wc = wave & 1;
    // 768 blocks; xcd = id%8 gets contiguous chunk of 96 = 4 A-panels x 24 B-panels (bijective, 768%8==0)
    const int id  = blockIdx.x;
    const int nid = (id & 7) * 96 + (id >> 3);
    const int mBase = (nid / 24) * BM;
    const int nBase = (nid % 24) * BN;

    floatx4 acc[4][4];
    #pragma unroll
    for (int i = 0; i < 4; i++)
        #pragma unroll
        for (int j = 0; j < 4; j++) acc[i][j] = fzero4();

    gemm_core(A, Bt, H_, mBase, nBase, tid, acc, As0, As1, Bs0, Bs1);

    const int col0 = lane & 15;
    const int r0   = (lane >> 4) * 4;
    const int hg   = (nBase + wc * 64) >> 6;   // global head index (wave-uniform)
    const int sec  = hg >> 4;                  // 0=q 1=k 2=v
    const int h    = hg & 15;

    float bs[4];
    #pragma unroll
    for (int nt = 0; nt < 4; nt++) bs[nt] = bias[nBase + wc * 64 + nt * 16 + col0];

    if (sec < 2) {
        unsigned short* dst = (sec == 0) ? Qo : Ko;
        const float if0 = __expf((float)col0        * (-0.2878231366f));   // j = col0
        const float if1 = __expf((float)(16 + col0) * (-0.2878231366f));   // j = 16+col0
        #pragma unroll
        for (int mt = 0; mt < 4; mt++) {
            #pragma unroll
            for (int reg = 0; reg < 4; reg++) {
                const int t  = mBase + wr * 64 + mt * 16 + r0 + reg;
                const int bb = t >> 11;
                const int s  = t & (S_ - 1);
                float sn0, cs0, sn1, cs1;
                __sincosf((float)s * if0, &sn0, &cs0);
                __sincosf((float)s * if1, &sn1, &cs1);
                const float v0 = acc[mt][0][reg] + bs[0];   // d = col0
                const float v1 = acc[mt][1][reg] + bs[1];   // d = 16+col0
                const float v2 = acc[mt][2][reg] + bs[2];   // d = 32+col0
                const float v3 = acc[mt][3][reg] + bs[3];   // d = 48+col0
                const float o0 = v0 * cs0 - v2 * sn0;
                const float o1 = v1 * cs1 - v3 * sn1;
                const float o2 = v2 * cs0 + v0 * sn0;
                const float o3 = v3 * cs1 + v1 * sn1;
                const size_t rb = ((size_t)(bb * NH_ + h) * S_ + s) * HD_;
                dst[rb +      col0] = f2bf_rn(o0);
                dst[rb + 16 + col0] = f2bf_rn(o1);
                dst[rb + 32 + col0] = f2bf_rn(o2);
                dst[rb + 48 + col0] = f2bf_rn(o3);
            }
        }
    } else {
        #pragma unroll
        for (int mt = 0; mt < 4; mt++) {
            const int t0 = mBase + wr * 64 + mt * 16 + r0;   // 4 consecutive tokens, 4-aligned
            const int bb = t0 >> 11;
            const int s0 = t0 & (S_ - 1);
            #pragma unroll
            for (int nt = 0; nt < 4; nt++) {
                const int d = nt * 16 + col0;
                ushort4 o;
                o.x = f2bf_rn(acc[mt][nt][0] + bs[nt]);
                o.y = f2bf_rn(acc[mt][nt][1] + bs[nt]);
                o.z = f2bf_rn(acc[mt][nt][2] + bs[nt]);
                o.w = f2bf_rn(acc[mt][nt][3] + bs[nt]);
                *reinterpret_cast<ushort4*>(&Vto[((size_t)(bb * NH_ + h) * HD_ + d) * S_ + s0]) = o;
            }
        }
    }
}

// ---------------------------------------------------------------- proj GEMM: 128x64 tiles, 1D grid + XCD swizzle
__global__ __launch_bounds__(256) void gemm_proj_k(const unsigned short* __restrict__ A,
                                                   const unsigned short* __restrict__ Bt,
                                                   const float* __restrict__ bias,
                                                   float* __restrict__ Cf,
                                                   int M, int N, int K) {
    __shared__ unsigned short As0[128 * 32], As1[128 * 32];
    __shared__ unsigned short Bs0[ 64 * 32], Bs1[ 64 * 32];

    const int tid  = threadIdx.x;
    const int lane = tid & 63;
    const int wave = tid >> 6;              // 0..3, owns rows wave*32..+31
    // 512 blocks; xcd = id%8 gets 64 = 4 A-panels x 16 B-panels (bijective, 512%8==0)
    const int id  = blockIdx.x;
    const int nid = (id & 7) * 64 + (id >> 3);
    const int mBase = (nid >> 4) * 128;
    const int nBase = (nid & 15) * 64;

    const int srow = lane >> 2;             // 0..15
    const int scol = (lane & 3) * 8;        // 0,8,16,24
    const int mrow = lane & 15;
    const int koff = (lane >> 4) * 8;

    floatx4 acc[2][4];
    #pragma unroll
    for (int i = 0; i < 2; i++)
        #pragma unroll
        for (int j = 0; j < 4; j++) acc[i][j] = fzero4();

    for (int kb = 0; kb < K; kb += 64) {
        __syncthreads();
        #pragma unroll
        for (int p = 0; p < 2; p++) {
            const int r = wave * 16 + p * 64;
            const size_t ga = (size_t)(mBase + r + srow) * K + kb + scol;
            gload_lds16(&A[ga],      &As0[r * 32]);
            gload_lds16(&A[ga + 32], &As1[r * 32]);
        }
        {
            const int r = wave * 16;
            const size_t gb = (size_t)(nBase + r + srow) * K + kb + scol;
            gload_lds16(&Bt[gb],      &Bs0[r * 32]);
            gload_lds16(&Bt[gb + 32], &Bs1[r * 32]);
        }
        __syncthreads();

        #pragma unroll
        for (int half = 0; half < 2; half++) {
            const unsigned short* As = half ? As1 : As0;
            const unsigned short* Bs = half ? Bs1 : Bs0;
            bf16x8 afrag[2], bfrag[4];
            #pragma unroll
            for (int mt = 0; mt < 2; mt++)
                afrag[mt] = *reinterpret_cast<const bf16x8*>(&As[(wave * 32 + mt * 16 + mrow) * 32 + koff]);
            #pragma unroll
            for (int nt = 0; nt < 4; nt++)
                bfrag[nt] = *reinterpret_cast<const bf16x8*>(&Bs[(nt * 16 + mrow) * 32 + koff]);
            #pragma unroll
            for (int mt = 0; mt < 2; mt++)
                #pragma unroll
                for (int nt = 0; nt < 4; nt++)
                    acc[mt][nt] = __builtin_amdgcn_mfma_f32_16x16x32_bf16(afrag[mt], bfrag[nt], acc[mt][nt], 0, 0, 0);
        }
    }

    const int col0 = lane & 15;
    const int r0   = (lane >> 4) * 4;
    #pragma unroll
    for (int mt = 0; mt < 2; mt++) {
        #pragma unroll
        for (int nt = 0; nt < 4; nt++) {
            const int gcol = nBase + nt * 16 + col0;
            const float bsv = bias[gcol];
            #pragma unroll
            for (int reg = 0; reg < 4; reg++) {
                const int grow = mBase + wave * 32 + mt * 16 + r0 + reg;
                Cf[(size_t)grow * N + gcol] = acc[mt][nt][reg] + bsv;
            }
        }
    }
}

// ---------------------------------------------------------------- flash attention: in-register P + LDS mask-bias table
// (unchanged from r7 — in-register P via swapped QK + key-permuted K staging, ones-A MFMA denominator,
// LDS bias table, setprio around PV cluster)
#define ALD 72
#define SCL2 0.1803368801f      /* 0.125 * log2(e) */
#define MNEG -14427.0f          /* -10000 * log2(e), causal fill */

__global__ __launch_bounds__(256, 4) void attn_k(const unsigned short* __restrict__ Q,
                                                 const unsigned short* __restrict__ Kg,
                                                 const unsigned short* __restrict__ Vt,
                                                 const int* __restrict__ mask,
                                                 unsigned short* __restrict__ ctx) {
    const int id = blockIdx.x;              // 0..1023
    const int bh = id & 31;                 // id%8 fixed per bh -> XCD locality
    const int v  = 31 - (id >> 5);          // q-tile index; most work first
    const int b  = bh >> 4;
    const int h  = bh & 15;
    const int tid  = threadIdx.x;
    const int lane = tid & 63;
    const int wave = tid >> 6;

    __shared__ unsigned short Ks [2][64 * ALD];   // 18.4 KB (key-permuted rows)
    __shared__ unsigned short Vts[2][64 * ALD];   // 18.4 KB (natural key order)
    __shared__ unsigned short Mb [S_];            //  4.0 KB bf16 mask-bias per key

    const size_t base = (size_t)bh * S_ * HD_;
    const int qbase = v * 64 + wave * 16;
    const int r16  = lane & 15;             // A-row / output-col lane index
    const int koff = (lane >> 4) * 8;       // d-offset in fragments / key-offset in PV reads
    const int g8   = (lane >> 4) * 8;       // key-group base for St quads
    const int qcol = qbase + r16;           // this lane's q row (output column)

    // ---- mask-bias table: 8 keys per thread, one b128 store; visible after first barrier
    {
        const int k0 = tid * 8;
        const int4 ma = *reinterpret_cast<const int4*>(&mask[b * S_ + k0]);
        const int4 mc = *reinterpret_cast<const int4*>(&mask[b * S_ + k0 + 4]);
        union { unsigned short us[8]; uint4 q; } pk;
        pk.us[0] = f2bf_rn((1.f - (float)ma.x) * MNEG);
        pk.us[1] = f2bf_rn((1.f - (float)ma.y) * MNEG);
        pk.us[2] = f2bf_rn((1.f - (float)ma.z) * MNEG);
        pk.us[3] = f2bf_rn((1.f - (float)ma.w) * MNEG);
        pk.us[4] = f2bf_rn((1.f - (float)mc.x) * MNEG);
        pk.us[5] = f2bf_rn((1.f - (float)mc.y) * MNEG);
        pk.us[6] = f2bf_rn((1.f - (float)mc.z) * MNEG);
        pk.us[7] = f2bf_rn((1.f - (float)mc.w) * MNEG);
        *reinterpret_cast<uint4*>(&Mb[k0]) = pk.q;
    }

    const bf16x8 qf0 = *reinterpret_cast<const bf16x8*>(&Q[base + (size_t)(qbase + r16) * HD_ + koff]);
    const bf16x8 qf1 = *reinterpret_cast<const bf16x8*>(&Q[base + (size_t)(qbase + r16) * HD_ + 32 + koff]);

    bf16x8 onesA;
    #pragma unroll
    for (int q = 0; q < 8; q++) onesA[q] = (__bf16)1.f;

    floatx4 Ot[4];                           // O^T: lane holds O^T[d=db*16+(lane>>4)*4+reg][q=qcol]
    #pragma unroll
    for (int db = 0; db < 4; db++) Ot[db] = fzero4();
    floatx4 Lacc = fzero4();                 // every row = column sum of P (ones-A MFMA)

    const int srow = tid >> 3;          // 0..31
    const int scol = (tid & 7) * 8;
    // key permutation within a 32-window: row r holds key pi(r)
    const int pi = ((srow & 12) << 1) | (srow & 3) | (((srow >> 4) & 1) << 2);

    // named prefetch registers for 2 tiles (no runtime-indexed arrays -> no scratch)
    uint4 k00, k01, k10, k11, v00, v01, v10, v11;
#define PF_TILE(TT, KR0, KR1, VR0, VR1) do {                                                   \
        const int kb_ = (TT) * 64;                                                             \
        KR0 = *reinterpret_cast<const uint4*>(&Kg[base + (size_t)(kb_ + pi)      * HD_ + scol]); \
        KR1 = *reinterpret_cast<const uint4*>(&Kg[base + (size_t)(kb_ + 32 + pi) * HD_ + scol]); \
        VR0 = *reinterpret_cast<const uint4*>(&Vt[base + (size_t)srow        * S_ + kb_ + scol]);  \
        VR1 = *reinterpret_cast<const uint4*>(&Vt[base + (size_t)(srow + 32) * S_ + kb_ + scol]);  \
    } while (0)
#define PREFETCH_MACRO(MI) do {                                                                \
        const int t0_ = min(2 * (MI), v);                                                      \
        const int t1_ = min(2 * (MI) + 1, v);                                                  \
        PF_TILE(t0_, k00, k01, v00, v01);                                                      \
        PF_TILE(t1_, k10, k11, v10, v11);                                                      \
    } while (0)

    const int nmac = (v + 2) >> 1;
    PREFETCH_MACRO(0);

    for (int mi = 0; mi < nmac; mi++) {
        if (mi) __syncthreads();                       // WAR: prior macro's LDS reads done
        *reinterpret_cast<uint4*>(&Ks [0][ srow       * ALD + scol]) = k00;
        *reinterpret_cast<uint4*>(&Ks [0][(srow + 32) * ALD + scol]) = k01;
        *reinterpret_cast<uint4*>(&Ks [1][ srow       * ALD + scol]) = k10;
        *reinterpret_cast<uint4*>(&Ks [1][(srow + 32) * ALD + scol]) = k11;
        *reinterpret_cast<uint4*>(&Vts[0][ srow       * ALD + scol]) = v00;
        *reinterpret_cast<uint4*>(&Vts[0][(srow + 32) * ALD + scol]) = v01;
        *reinterpret_cast<uint4*>(&Vts[1][ srow       * ALD + scol]) = v10;
        *reinterpret_cast<uint4*>(&Vts[1][(srow + 32) * ALD + scol]) = v11;
        __syncthreads();                               // staged tiles + (mi==0) Mb table visible
        if (mi + 1 < nmac) PREFETCH_MACRO(mi + 1);

        #pragma unroll
        for (int half = 0; half < 2; half++) {
            const int kt = 2 * mi + half;
            if (half && kt > v) continue;              // wave-uniform skip (odd tile count)
            const int kb = kt * 64;
            const unsigned short* ks = Ks [half];
            const unsigned short* vs = Vts[half];

            // ---- per-tile bias: four 8B broadcast LDS reads, latency hidden under QK
            const unsigned short* mbp = &Mb[kb + g8];
            const ushort4 b00 = *reinterpret_cast<const ushort4*>(mbp);        // w0 ab0
            const ushort4 b01 = *reinterpret_cast<const ushort4*>(mbp + 4);    // w0 ab1
            const ushort4 b10 = *reinterpret_cast<const ushort4*>(mbp + 32);   // w1 ab0
            const ushort4 b11 = *reinterpret_cast<const ushort4*>(mbp + 36);   // w1 ab1

            #pragma unroll
            for (int w = 0; w < 2; w++) {              // two 32-key windows
                float p[2][4];
                #pragma unroll
                for (int ab = 0; ab < 2; ab++) {
                    const int nt = w * 2 + ab;
                    // St = K·Q^T over permuted K rows; quad reg -> key kb + w*32 + ab*4 + 8g + reg
                    const bf16x8 kf0 = *reinterpret_cast<const bf16x8*>(&ks[(nt * 16 + r16) * ALD + koff]);
                    const bf16x8 kf1 = *reinterpret_cast<const bf16x8*>(&ks[(nt * 16 + r16) * ALD + 32 + koff]);
                    floatx4 c = fzero4();
                    c = __builtin_amdgcn_mfma_f32_16x16x32_bf16(kf0, qf0, c, 0, 0, 0);
                    c = __builtin_amdgcn_mfma_f32_16x16x32_bf16(kf1, qf1, c, 0, 0, 0);
                    const ushort4 bb = w ? (ab ? b11 : b10) : (ab ? b01 : b00);
                    const int kbase = kb + w * 32 + ab * 4 + g8;
                    float sc0 = c[0] * SCL2 + bf2f(bb.x);
                    float sc1 = c[1] * SCL2 + bf2f(bb.y);
                    float sc2 = c[2] * SCL2 + bf2f(bb.z);
                    float sc3 = c[3] * SCL2 + bf2f(bb.w);
                    if (kt == v) {                     // causal on diagonal tile only
                        if (kbase + 0 > qcol) sc0 = MNEG;
                        if (kbase + 1 > qcol) sc1 = MNEG;
                        if (kbase + 2 > qcol) sc2 = MNEG;
                        if (kbase + 3 > qcol) sc3 = MNEG;
                    }
                    p[ab][0] = exp2f(sc0);
                    p[ab][1] = exp2f(sc1);
                    p[ab][2] = exp2f(sc2);
                    p[ab][3] = exp2f(sc3);
                }
                // pack P fragment: keys w*32 + 8g + {0..7} in order
                union { uint4 u; bf16x8 v; } pf;
                pf.u.x = cvtpk_bf16(p[0][0], p[0][1]);
                pf.u.y = cvtpk_bf16(p[0][2], p[0][3]);
                pf.u.z = cvtpk_bf16(p[1][0], p[1][1]);
                pf.u.w = cvtpk_bf16(p[1][2], p[1][3]);
                // PV: O^T += V^T · P^T (V natural key order, contiguous reads); L via ones-A MFMA
                __builtin_amdgcn_s_setprio(1);
                #pragma unroll
                for (int db = 0; db < 4; db++) {
                    const bf16x8 vf = *reinterpret_cast<const bf16x8*>(&vs[(db * 16 + r16) * ALD + w * 32 + koff]);
                    Ot[db] = __builtin_amdgcn_mfma_f32_16x16x32_bf16(vf, pf.v, Ot[db], 0, 0, 0);
                }
                Lacc = __builtin_amdgcn_mfma_f32_16x16x32_bf16(onesA, pf.v, Lacc, 0, 0, 0);
                __builtin_amdgcn_s_setprio(0);
            }
        }
    }
#undef PREFETCH_MACRO
#undef PF_TILE

    // epilogue: Lacc rows all equal the full column sum — no cross-lane reduce needed
    const float rl = 1.f / Lacc[0];
    const int r4 = (lane >> 4) * 4;
    #pragma unroll
    for (int db = 0; db < 4; db++) {
        ushort4 o;
        o.x = f2bf_rn(Ot[db][0] * rl);
        o.y = f2bf_rn(Ot[db][1] * rl);
        o.z = f2bf_rn(Ot[db][2] * rl);
        o.w = f2bf_rn(Ot[db][3] * rl);
        *reinterpret_cast<ushort4*>(&ctx[((size_t)b * S_ + qcol) * H_ + h * HD_ + db * 16 + r4]) = o;
    }
}

// ---------------------------------------------------------------- launch
extern "C" void kernel_launch(void* const* d_in, const int* in_sizes, int n_in,
                              void* d_out, int out_size, void* d_ws, size_t ws_size,
                              hipStream_t stream) {
    const float* x     = (const float*)d_in[0];
    const int*   mask  = (const int*)d_in[1];
    const float* normw = (const float*)d_in[2];
    const float* normb = (const float*)d_in[3];
    const float* qkvw  = (const float*)d_in[4];
    const float* qkvb  = (const float*)d_in[5];
    const float* ow    = (const float*)d_in[6];
    const float* ob    = (const float*)d_in[7];
    float* out = (float*)d_out;

    char* ws = (char*)d_ws;
    unsigned short* xn_bf   = (unsigned short*)(ws);                      //  8 MB
    unsigned short* qkvwT   = (unsigned short*)(ws + (8ull  << 20));      //  6 MB
    unsigned short* owT     = (unsigned short*)(ws + (14ull << 20));      //  2 MB
    unsigned short* Qb      = (unsigned short*)(ws + (16ull << 20));      //  8 MB [bh][s][d]
    unsigned short* Kb      = (unsigned short*)(ws + (24ull << 20));      //  8 MB [bh][s][d]
    unsigned short* Vtb     = (unsigned short*)(ws + (32ull << 20));      //  8 MB [bh][d][s]
    unsigned short* ctx_bf  = (unsigned short*)(ws + (40ull << 20));      //  8 MB

    pre_k<<<1024 + T_, 256, 0, stream>>>(qkvw, ow, qkvwT, owT, x, normw, normb, xn_bf);
    gemm_qkv_k<<<768, 256, 0, stream>>>(xn_bf, qkvwT, qkvb, Qb, Kb, Vtb);
    attn_k<<<1024, 256, 0, stream>>>(Qb, Kb, Vtb, mask, ctx_bf);
    gemm_proj_k<<<512, 256, 0, stream>>>(ctx_bf, owT, ob, out, T_, H_, H_);
}

// Round 9
// 188.274 us; speedup vs baseline: 1.1112x; 1.0098x over previous
//
#include <hip/hip_runtime.h>
#include <hip/hip_bf16.h>

#define B_  2
#define S_  2048
#define H_  1024
#define NH_ 16
#define HD_ 64
#define T_  (B_*S_)     // 4096 tokens
#define H3_ (3*H_)      // 3072

typedef float  floatx4 __attribute__((ext_vector_type(4)));
typedef __bf16 bf16x8  __attribute__((ext_vector_type(8)));

__device__ inline unsigned short f2bf_rn(float f) {
    union { float f; unsigned int u; } v; v.f = f;
    unsigned int u = v.u;
    u += 0x7fffu + ((u >> 16) & 1u);
    return (unsigned short)(u >> 16);
}
__device__ inline floatx4 fzero4() { floatx4 v; v[0]=0.f; v[1]=0.f; v[2]=0.f; v[3]=0.f; return v; }

__device__ inline float bf2f(unsigned short u) {
    union { unsigned int i; float f; } x; x.i = ((unsigned int)u) << 16; return x.f;
}

// pack two f32 -> one u32 of two bf16 (lo = src0), RNE; no builtin on gfx950 -> inline asm
__device__ inline unsigned int cvtpk_bf16(float lo, float hi) {
    unsigned int r;
    asm("v_cvt_pk_bf16_f32 %0, %1, %2" : "=v"(r) : "v"(lo), "v"(hi));
    return r;
}

// async global->LDS, 16B per lane; LDS dest = wave-uniform base + lane*16
__device__ inline void gload_lds16(const unsigned short* g, unsigned short* l) {
    __builtin_amdgcn_global_load_lds((const __attribute__((address_space(1))) unsigned int*)g,
                                     (__attribute__((address_space(3))) unsigned int*)l,
                                     16, 0, 0);
}

// ---------------------------------------------------------------- fused preprocessing: weight cast+transpose AND LayerNorm
// blocks 0..1023: cvt (768 qkvw tiles + 256 ow tiles); blocks 1024..5119: LN (one token each).
#define TLD 72
__global__ __launch_bounds__(256) void pre_k(const float* __restrict__ qkvw,
                                             const float* __restrict__ ow,
                                             unsigned short* __restrict__ qkvwT,
                                             unsigned short* __restrict__ owT,
                                             const float* __restrict__ x,
                                             const float* __restrict__ nw,
                                             const float* __restrict__ nb,
                                             unsigned short* __restrict__ xn) {
    const int tid = threadIdx.x;
    if (blockIdx.x < 1024) {
        __shared__ unsigned short Ts[64 * TLD];
        int id = blockIdx.x;
        const float* W; unsigned short* Wt; int N, nbs, kb;
        if (id < 768) { W = qkvw; Wt = qkvwT; N = H3_; nbs = (id % 48) * 64; kb = (id / 48) * 64; }
        else { id -= 768; W = ow; Wt = owT; N = H_; nbs = (id % 16) * 64; kb = (id / 16) * 64; }
        const int K = H_;
        #pragma unroll
        for (int p = 0; p < 4; p++) {
            const int krow = kb + p * 16 + (tid >> 4);
            const int ncol = (tid & 15) * 4;
            const float4 w = *reinterpret_cast<const float4*>(&W[(size_t)krow * N + nbs + ncol]);
            Ts[(ncol + 0) * TLD + p * 16 + (tid >> 4)] = f2bf_rn(w.x);
            Ts[(ncol + 1) * TLD + p * 16 + (tid >> 4)] = f2bf_rn(w.y);
            Ts[(ncol + 2) * TLD + p * 16 + (tid >> 4)] = f2bf_rn(w.z);
            Ts[(ncol + 3) * TLD + p * 16 + (tid >> 4)] = f2bf_rn(w.w);
        }
        __syncthreads();
        #pragma unroll
        for (int p = 0; p < 2; p++) {
            const int n = (tid >> 3) + p * 32;
            const int k8 = (tid & 7) * 8;
            const uint4 v = *reinterpret_cast<const uint4*>(&Ts[n * TLD + k8]);
            *reinterpret_cast<uint4*>(&Wt[(size_t)(nbs + n) * K + kb + k8]) = v;
        }
    } else {
        const int t = blockIdx.x - 1024;
        const float4 v = reinterpret_cast<const float4*>(x + (size_t)t * H_)[tid];
        float s  = v.x + v.y + v.z + v.w;
        float s2 = v.x*v.x + v.y*v.y + v.z*v.z + v.w*v.w;
        for (int off = 32; off > 0; off >>= 1) {
            s  += __shfl_down(s,  off, 64);
            s2 += __shfl_down(s2, off, 64);
        }
        __shared__ float red[8];
        const int wave = tid >> 6, lane = tid & 63;
        if (lane == 0) { red[wave] = s; red[4 + wave] = s2; }
        __syncthreads();
        if (tid == 0) {
            red[0] = red[0] + red[1] + red[2] + red[3];
            red[4] = red[4] + red[5] + red[6] + red[7];
        }
        __syncthreads();
        const float mean = red[0] * (1.f / H_);
        const float var  = red[4] * (1.f / H_) - mean * mean;
        const float rstd = rsqrtf(var + 1e-5f);
        const float4 wv = reinterpret_cast<const float4*>(nw)[tid];
        const float4 bv = reinterpret_cast<const float4*>(nb)[tid];
        ushort4 o = make_ushort4(f2bf_rn((v.x - mean) * rstd * wv.x + bv.x),
                                 f2bf_rn((v.y - mean) * rstd * wv.y + bv.y),
                                 f2bf_rn((v.z - mean) * rstd * wv.z + bv.z),
                                 f2bf_rn((v.w - mean) * rstd * wv.w + bv.w));
        reinterpret_cast<ushort4*>(xn + (size_t)t * H_)[tid] = o;
    }
}

// ---------------------------------------------------------------- shared GEMM core: BK=64 as two BK=32 sub-buffers
#define BM 128
#define BN 128

__device__ inline void gemm_core(const unsigned short* __restrict__ A,
                                 const unsigned short* __restrict__ Bt,
                                 int K, int mBase, int nBase,
                                 int tid, floatx4 acc[4][4],
                                 unsigned short* As0, unsigned short* As1,
                                 unsigned short* Bs0, unsigned short* Bs1) {
    const int lane = tid & 63;
    const int wave = tid >> 6;
    const int wr = wave >> 1, wc = wave & 1;
    const int srow = lane >> 2;        // 0..15
    const int scol = (lane & 3) * 8;   // 0,8,16,24
    const int mrow = lane & 15;
    const int koff = (lane >> 4) * 8;

    for (int kb = 0; kb < K; kb += 64) {
        __syncthreads();
        #pragma unroll
        for (int p = 0; p < 2; p++) {
            const int r = wave * 16 + p * 64;
            const size_t ga = (size_t)(mBase + r + srow) * K + kb + scol;
            const size_t gb = (size_t)(nBase + r + srow) * K + kb + scol;
            gload_lds16(&A [ga],      &As0[r * 32]);
            gload_lds16(&A [ga + 32], &As1[r * 32]);
            gload_lds16(&Bt[gb],      &Bs0[r * 32]);
            gload_lds16(&Bt[gb + 32], &Bs1[r * 32]);
        }
        __syncthreads();

        #pragma unroll
        for (int half = 0; half < 2; half++) {
            const unsigned short* As = half ? As1 : As0;
            const unsigned short* Bs = half ? Bs1 : Bs0;
            bf16x8 afrag[4], bfrag[4];
            #pragma unroll
            for (int mt = 0; mt < 4; mt++)
                afrag[mt] = *reinterpret_cast<const bf16x8*>(&As[(wr * 64 + mt * 16 + mrow) * 32 + koff]);
            #pragma unroll
            for (int nt = 0; nt < 4; nt++)
                bfrag[nt] = *reinterpret_cast<const bf16x8*>(&Bs[(wc * 64 + nt * 16 + mrow) * 32 + koff]);
            #pragma unroll
            for (int mt = 0; mt < 4; mt++)
                #pragma unroll
                for (int nt = 0; nt < 4; nt++)
                    acc[mt][nt] = __builtin_amdgcn_mfma_f32_16x16x32_bf16(afrag[mt], bfrag[nt], acc[mt][nt], 0, 0, 0);
        }
    }
}

// ---------------------------------------------------------------- QKV GEMM (2D grid — r7 config: 46.2us, FETCH 40MB;
// x-major dispatch gives each XCD 3 fixed B-panels (L2-resident) + lockstep A-panel walk (L3 dedup).
// r8's A-panel-per-XCD swizzle measured WORSE: 59.3us, FETCH 54MB — reverted.)
__global__ __launch_bounds__(256) void gemm_qkv_k(const unsigned short* __restrict__ A,
                                                  const unsigned short* __restrict__ Bt,
                                                  const float* __restrict__ bias,
                                                  unsigned short* __restrict__ Qo,
                                                  unsigned short* __restrict__ Ko,
                                                  unsigned short* __restrict__ Vto) {
    __shared__ unsigned short As0[BM * 32], As1[BM * 32];
    __shared__ unsigned short Bs0[BN * 32], Bs1[BN * 32];

    const int tid  = threadIdx.x;
    const int lane = tid & 63;
    const int wave = tid >> 6;
    const int wr = wave >> 1, wc = wave & 1;
    const int mBase = blockIdx.y * BM;
    const int nBase = blockIdx.x * BN;

    floatx4 acc[4][4];
    #pragma unroll
    for (int i = 0; i < 4; i++)
        #pragma unroll
        for (int j = 0; j < 4; j++) acc[i][j] = fzero4();

    gemm_core(A, Bt, H_, mBase, nBase, tid, acc, As0, As1, Bs0, Bs1);

    const int col0 = lane & 15;
    const int r0   = (lane >> 4) * 4;
    const int hg   = (nBase + wc * 64) >> 6;   // global head index (wave-uniform)
    const int sec  = hg >> 4;                  // 0=q 1=k 2=v
    const int h    = hg & 15;

    float bs[4];
    #pragma unroll
    for (int nt = 0; nt < 4; nt++) bs[nt] = bias[nBase + wc * 64 + nt * 16 + col0];

    if (sec < 2) {
        unsigned short* dst = (sec == 0) ? Qo : Ko;
        const float if0 = __expf((float)col0        * (-0.2878231366f));   // j = col0
        const float if1 = __expf((float)(16 + col0) * (-0.2878231366f));   // j = 16+col0
        #pragma unroll
        for (int mt = 0; mt < 4; mt++) {
            #pragma unroll
            for (int reg = 0; reg < 4; reg++) {
                const int t  = mBase + wr * 64 + mt * 16 + r0 + reg;
                const int bb = t >> 11;
                const int s  = t & (S_ - 1);
                float sn0, cs0, sn1, cs1;
                __sincosf((float)s * if0, &sn0, &cs0);
                __sincosf((float)s * if1, &sn1, &cs1);
                const float v0 = acc[mt][0][reg] + bs[0];   // d = col0
                const float v1 = acc[mt][1][reg] + bs[1];   // d = 16+col0
                const float v2 = acc[mt][2][reg] + bs[2];   // d = 32+col0
                const float v3 = acc[mt][3][reg] + bs[3];   // d = 48+col0
                const float o0 = v0 * cs0 - v2 * sn0;
                const float o1 = v1 * cs1 - v3 * sn1;
                const float o2 = v2 * cs0 + v0 * sn0;
                const float o3 = v3 * cs1 + v1 * sn1;
                const size_t rb = ((size_t)(bb * NH_ + h) * S_ + s) * HD_;
                dst[rb +      col0] = f2bf_rn(o0);
                dst[rb + 16 + col0] = f2bf_rn(o1);
                dst[rb + 32 + col0] = f2bf_rn(o2);
                dst[rb + 48 + col0] = f2bf_rn(o3);
            }
        }
    } else {
        #pragma unroll
        for (int mt = 0; mt < 4; mt++) {
            const int t0 = mBase + wr * 64 + mt * 16 + r0;   // 4 consecutive tokens, 4-aligned
            const int bb = t0 >> 11;
            const int s0 = t0 & (S_ - 1);
            #pragma unroll
            for (int nt = 0; nt < 4; nt++) {
                const int d = nt * 16 + col0;
                ushort4 o;
                o.x = f2bf_rn(acc[mt][nt][0] + bs[nt]);
                o.y = f2bf_rn(acc[mt][nt][1] + bs[nt]);
                o.z = f2bf_rn(acc[mt][nt][2] + bs[nt]);
                o.w = f2bf_rn(acc[mt][nt][3] + bs[nt]);
                *reinterpret_cast<ushort4*>(&Vto[((size_t)(bb * NH_ + h) * HD_ + d) * S_ + s0]) = o;
            }
        }
    }
}

// ---------------------------------------------------------------- proj GEMM: 128x64 tiles, 1D grid + XCD swizzle (r8 config)
__global__ __launch_bounds__(256) void gemm_proj_k(const unsigned short* __restrict__ A,
                                                   const unsigned short* __restrict__ Bt,
                                                   const float* __restrict__ bias,
                                                   float* __restrict__ Cf,
                                                   int M, int N, int K) {
    __shared__ unsigned short As0[128 * 32], As1[128 * 32];
    __shared__ unsigned short Bs0[ 64 * 32], Bs1[ 64 * 32];

    const int tid  = threadIdx.x;
    const int lane = tid & 63;
    const int wave = tid >> 6;              // 0..3, owns rows wave*32..+31
    const int id  = blockIdx.x;
    const int nid = (id & 7) * 64 + (id >> 3);
    const int mBase = (nid >> 4) * 128;
    const int nBase = (nid & 15) * 64;

    const int srow = lane >> 2;             // 0..15
    const int scol = (lane & 3) * 8;        // 0,8,16,24
    const int mrow = lane & 15;
    const int koff = (lane >> 4) * 8;

    floatx4 acc[2][4];
    #pragma unroll
    for (int i = 0; i < 2; i++)
        #pragma unroll
        for (int j = 0; j < 4; j++) acc[i][j] = fzero4();

    for (int kb = 0; kb < K; kb += 64) {
        __syncthreads();
        #pragma unroll
        for (int p = 0; p < 2; p++) {
            const int r = wave * 16 + p * 64;
            const size_t ga = (size_t)(mBase + r + srow) * K + kb + scol;
            gload_lds16(&A[ga],      &As0[r * 32]);
            gload_lds16(&A[ga + 32], &As1[r * 32]);
        }
        {
            const int r = wave * 16;
            const size_t gb = (size_t)(nBase + r + srow) * K + kb + scol;
            gload_lds16(&Bt[gb],      &Bs0[r * 32]);
            gload_lds16(&Bt[gb + 32], &Bs1[r * 32]);
        }
        __syncthreads();

        #pragma unroll
        for (int half = 0; half < 2; half++) {
            const unsigned short* As = half ? As1 : As0;
            const unsigned short* Bs = half ? Bs1 : Bs0;
            bf16x8 afrag[2], bfrag[4];
            #pragma unroll
            for (int mt = 0; mt < 2; mt++)
                afrag[mt] = *reinterpret_cast<const bf16x8*>(&As[(wave * 32 + mt * 16 + mrow) * 32 + koff]);
            #pragma unroll
            for (int nt = 0; nt < 4; nt++)
                bfrag[nt] = *reinterpret_cast<const bf16x8*>(&Bs[(nt * 16 + mrow) * 32 + koff]);
            #pragma unroll
            for (int mt = 0; mt < 2; mt++)
                #pragma unroll
                for (int nt = 0; nt < 4; nt++)
                    acc[mt][nt] = __builtin_amdgcn_mfma_f32_16x16x32_bf16(afrag[mt], bfrag[nt], acc[mt][nt], 0, 0, 0);
        }
    }

    const int col0 = lane & 15;
    const int r0   = (lane >> 4) * 4;
    #pragma unroll
    for (int mt = 0; mt < 2; mt++) {
        #pragma unroll
        for (int nt = 0; nt < 4; nt++) {
            const int gcol = nBase + nt * 16 + col0;
            const float bsv = bias[gcol];
            #pragma unroll
            for (int reg = 0; reg < 4; reg++) {
                const int grow = mBase + wave * 32 + mt * 16 + r0 + reg;
                Cf[(size_t)grow * N + gcol] = acc[mt][nt][reg] + bsv;
            }
        }
    }
}

// ---------------------------------------------------------------- flash attention: in-register P + LDS mask-bias table
// (unchanged from r7 — in-register P via swapped QK + key-permuted K staging, ones-A MFMA denominator,
// LDS bias table, setprio around PV cluster)
#define ALD 72
#define SCL2 0.1803368801f      /* 0.125 * log2(e) */
#define MNEG -14427.0f          /* -10000 * log2(e), causal fill */

__global__ __launch_bounds__(256, 4) void attn_k(const unsigned short* __restrict__ Q,
                                                 const unsigned short* __restrict__ Kg,
                                                 const unsigned short* __restrict__ Vt,
                                                 const int* __restrict__ mask,
                                                 unsigned short* __restrict__ ctx) {
    const int id = blockIdx.x;              // 0..1023
    const int bh = id & 31;                 // id%8 fixed per bh -> XCD locality
    const int v  = 31 - (id >> 5);          // q-tile index; most work first
    const int b  = bh >> 4;
    const int h  = bh & 15;
    const int tid  = threadIdx.x;
    const int lane = tid & 63;
    const int wave = tid >> 6;

    __shared__ unsigned short Ks [2][64 * ALD];   // 18.4 KB (key-permuted rows)
    __shared__ unsigned short Vts[2][64 * ALD];   // 18.4 KB (natural key order)
    __shared__ unsigned short Mb [S_];            //  4.0 KB bf16 mask-bias per key

    const size_t base = (size_t)bh * S_ * HD_;
    const int qbase = v * 64 + wave * 16;
    const int r16  = lane & 15;             // A-row / output-col lane index
    const int koff = (lane >> 4) * 8;       // d-offset in fragments / key-offset in PV reads
    const int g8   = (lane >> 4) * 8;       // key-group base for St quads
    const int qcol = qbase + r16;           // this lane's q row (output column)

    // ---- mask-bias table: 8 keys per thread, one b128 store; visible after first barrier
    {
        const int k0 = tid * 8;
        const int4 ma = *reinterpret_cast<const int4*>(&mask[b * S_ + k0]);
        const int4 mc = *reinterpret_cast<const int4*>(&mask[b * S_ + k0 + 4]);
        union { unsigned short us[8]; uint4 q; } pk;
        pk.us[0] = f2bf_rn((1.f - (float)ma.x) * MNEG);
        pk.us[1] = f2bf_rn((1.f - (float)ma.y) * MNEG);
        pk.us[2] = f2bf_rn((1.f - (float)ma.z) * MNEG);
        pk.us[3] = f2bf_rn((1.f - (float)ma.w) * MNEG);
        pk.us[4] = f2bf_rn((1.f - (float)mc.x) * MNEG);
        pk.us[5] = f2bf_rn((1.f - (float)mc.y) * MNEG);
        pk.us[6] = f2bf_rn((1.f - (float)mc.z) * MNEG);
        pk.us[7] = f2bf_rn((1.f - (float)mc.w) * MNEG);
        *reinterpret_cast<uint4*>(&Mb[k0]) = pk.q;
    }

    const bf16x8 qf0 = *reinterpret_cast<const bf16x8*>(&Q[base + (size_t)(qbase + r16) * HD_ + koff]);
    const bf16x8 qf1 = *reinterpret_cast<const bf16x8*>(&Q[base + (size_t)(qbase + r16) * HD_ + 32 + koff]);

    bf16x8 onesA;
    #pragma unroll
    for (int q = 0; q < 8; q++) onesA[q] = (__bf16)1.f;

    floatx4 Ot[4];                           // O^T: lane holds O^T[d=db*16+(lane>>4)*4+reg][q=qcol]
    #pragma unroll
    for (int db = 0; db < 4; db++) Ot[db] = fzero4();
    floatx4 Lacc = fzero4();                 // every row = column sum of P (ones-A MFMA)

    const int srow = tid >> 3;          // 0..31
    const int scol = (tid & 7) * 8;
    // key permutation within a 32-window: row r holds key pi(r)
    const int pi = ((srow & 12) << 1) | (srow & 3) | (((srow >> 4) & 1) << 2);

    // named prefetch registers for 2 tiles (no runtime-indexed arrays -> no scratch)
    uint4 k00, k01, k10, k11, v00, v01, v10, v11;
#define PF_TILE(TT, KR0, KR1, VR0, VR1) do {                                                   \
        const int kb_ = (TT) * 64;                                                             \
        KR0 = *reinterpret_cast<const uint4*>(&Kg[base + (size_t)(kb_ + pi)      * HD_ + scol]); \
        KR1 = *reinterpret_cast<const uint4*>(&Kg[base + (size_t)(kb_ + 32 + pi) * HD_ + scol]); \
        VR0 = *reinterpret_cast<const uint4*>(&Vt[base + (size_t)srow        * S_ + kb_ + scol]);  \
        VR1 = *reinterpret_cast<const uint4*>(&Vt[base + (size_t)(srow + 32) * S_ + kb_ + scol]);  \
    } while (0)
#define PREFETCH_MACRO(MI) do {                                                                \
        const int t0_ = min(2 * (MI), v);                                                      \
        const int t1_ = min(2 * (MI) + 1, v);                                                  \
        PF_TILE(t0_, k00, k01, v00, v01);                                                      \
        PF_TILE(t1_, k10, k11, v10, v11);                                                      \
    } while (0)

    const int nmac = (v + 2) >> 1;
    PREFETCH_MACRO(0);

    for (int mi = 0; mi < nmac; mi++) {
        if (mi) __syncthreads();                       // WAR: prior macro's LDS reads done
        *reinterpret_cast<uint4*>(&Ks [0][ srow       * ALD + scol]) = k00;
        *reinterpret_cast<uint4*>(&Ks [0][(srow + 32) * ALD + scol]) = k01;
        *reinterpret_cast<uint4*>(&Ks [1][ srow       * ALD + scol]) = k10;
        *reinterpret_cast<uint4*>(&Ks [1][(srow + 32) * ALD + scol]) = k11;
        *reinterpret_cast<uint4*>(&Vts[0][ srow       * ALD + scol]) = v00;
        *reinterpret_cast<uint4*>(&Vts[0][(srow + 32) * ALD + scol]) = v01;
        *reinterpret_cast<uint4*>(&Vts[1][ srow       * ALD + scol]) = v10;
        *reinterpret_cast<uint4*>(&Vts[1][(srow + 32) * ALD + scol]) = v11;
        __syncthreads();                               // staged tiles + (mi==0) Mb table visible
        if (mi + 1 < nmac) PREFETCH_MACRO(mi + 1);

        #pragma unroll
        for (int half = 0; half < 2; half++) {
            const int kt = 2 * mi + half;
            if (half && kt > v) continue;              // wave-uniform skip (odd tile count)
            const int kb = kt * 64;
            const unsigned short* ks = Ks [half];
            const unsigned short* vs = Vts[half];

            // ---- per-tile bias: four 8B broadcast LDS reads, latency hidden under QK
            const unsigned short* mbp = &Mb[kb + g8];
            const ushort4 b00 = *reinterpret_cast<const ushort4*>(mbp);        // w0 ab0
            const ushort4 b01 = *reinterpret_cast<const ushort4*>(mbp + 4);    // w0 ab1
            const ushort4 b10 = *reinterpret_cast<const ushort4*>(mbp + 32);   // w1 ab0
            const ushort4 b11 = *reinterpret_cast<const ushort4*>(mbp + 36);   // w1 ab1

            #pragma unroll
            for (int w = 0; w < 2; w++) {              // two 32-key windows
                float p[2][4];
                #pragma unroll
                for (int ab = 0; ab < 2; ab++) {
                    const int nt = w * 2 + ab;
                    // St = K·Q^T over permuted K rows; quad reg -> key kb + w*32 + ab*4 + 8g + reg
                    const bf16x8 kf0 = *reinterpret_cast<const bf16x8*>(&ks[(nt * 16 + r16) * ALD + koff]);
                    const bf16x8 kf1 = *reinterpret_cast<const bf16x8*>(&ks[(nt * 16 + r16) * ALD + 32 + koff]);
                    floatx4 c = fzero4();
                    c = __builtin_amdgcn_mfma_f32_16x16x32_bf16(kf0, qf0, c, 0, 0, 0);
                    c = __builtin_amdgcn_mfma_f32_16x16x32_bf16(kf1, qf1, c, 0, 0, 0);
                    const ushort4 bb = w ? (ab ? b11 : b10) : (ab ? b01 : b00);
                    const int kbase = kb + w * 32 + ab * 4 + g8;
                    float sc0 = c[0] * SCL2 + bf2f(bb.x);
                    float sc1 = c[1] * SCL2 + bf2f(bb.y);
                    float sc2 = c[2] * SCL2 + bf2f(bb.z);
                    float sc3 = c[3] * SCL2 + bf2f(bb.w);
                    if (kt == v) {                     // causal on diagonal tile only
                        if (kbase + 0 > qcol) sc0 = MNEG;
                        if (kbase + 1 > qcol) sc1 = MNEG;
                        if (kbase + 2 > qcol) sc2 = MNEG;
                        if (kbase + 3 > qcol) sc3 = MNEG;
                    }
                    p[ab][0] = exp2f(sc0);
                    p[ab][1] = exp2f(sc1);
                    p[ab][2] = exp2f(sc2);
                    p[ab][3] = exp2f(sc3);
                }
                // pack P fragment: keys w*32 + 8g + {0..7} in order
                union { uint4 u; bf16x8 v; } pf;
                pf.u.x = cvtpk_bf16(p[0][0], p[0][1]);
                pf.u.y = cvtpk_bf16(p[0][2], p[0][3]);
                pf.u.z = cvtpk_bf16(p[1][0], p[1][1]);
                pf.u.w = cvtpk_bf16(p[1][2], p[1][3]);
                // PV: O^T += V^T · P^T (V natural key order, contiguous reads); L via ones-A MFMA
                __builtin_amdgcn_s_setprio(1);
                #pragma unroll
                for (int db = 0; db < 4; db++) {
                    const bf16x8 vf = *reinterpret_cast<const bf16x8*>(&vs[(db * 16 + r16) * ALD + w * 32 + koff]);
                    Ot[db] = __builtin_amdgcn_mfma_f32_16x16x32_bf16(vf, pf.v, Ot[db], 0, 0, 0);
                }
                Lacc = __builtin_amdgcn_mfma_f32_16x16x32_bf16(onesA, pf.v, Lacc, 0, 0, 0);
                __builtin_amdgcn_s_setprio(0);
            }
        }
    }
#undef PREFETCH_MACRO
#undef PF_TILE

    // epilogue: Lacc rows all equal the full column sum — no cross-lane reduce needed
    const float rl = 1.f / Lacc[0];
    const int r4 = (lane >> 4) * 4;
    #pragma unroll
    for (int db = 0; db < 4; db++) {
        ushort4 o;
        o.x = f2bf_rn(Ot[db][0] * rl);
        o.y = f2bf_rn(Ot[db][1] * rl);
        o.z = f2bf_rn(Ot[db][2] * rl);
        o.w = f2bf_rn(Ot[db][3] * rl);
        *reinterpret_cast<ushort4*>(&ctx[((size_t)b * S_ + qcol) * H_ + h * HD_ + db * 16 + r4]) = o;
    }
}

// ---------------------------------------------------------------- launch
extern "C" void kernel_launch(void* const* d_in, const int* in_sizes, int n_in,
                              void* d_out, int out_size, void* d_ws, size_t ws_size,
                              hipStream_t stream) {
    const float* x     = (const float*)d_in[0];
    const int*   mask  = (const int*)d_in[1];
    const float* normw = (const float*)d_in[2];
    const float* normb = (const float*)d_in[3];
    const float* qkvw  = (const float*)d_in[4];
    const float* qkvb  = (const float*)d_in[5];
    const float* ow    = (const float*)d_in[6];
    const float* ob    = (const float*)d_in[7];
    float* out = (float*)d_out;

    char* ws = (char*)d_ws;
    unsigned short* xn_bf   = (unsigned short*)(ws);                      //  8 MB
    unsigned short* qkvwT   = (unsigned short*)(ws + (8ull  << 20));      //  6 MB
    unsigned short* owT     = (unsigned short*)(ws + (14ull << 20));      //  2 MB
    unsigned short* Qb      = (unsigned short*)(ws + (16ull << 20));      //  8 MB [bh][s][d]
    unsigned short* Kb      = (unsigned short*)(ws + (24ull << 20));      //  8 MB [bh][s][d]
    unsigned short* Vtb     = (unsigned short*)(ws + (32ull << 20));      //  8 MB [bh][d][s]
    unsigned short* ctx_bf  = (unsigned short*)(ws + (40ull << 20));      //  8 MB

    pre_k<<<1024 + T_, 256, 0, stream>>>(qkvw, ow, qkvwT, owT, x, normw, normb, xn_bf);
    gemm_qkv_k<<<dim3(H3_ / BN, T_ / BM), 256, 0, stream>>>(xn_bf, qkvwT, qkvb, Qb, Kb, Vtb);
    attn_k<<<1024, 256, 0, stream>>>(Qb, Kb, Vtb, mask, ctx_bf);
    gemm_proj_k<<<512, 256, 0, stream>>>(ctx_bf, owT, ob, out, T_, H_, H_);
}

// Round 10
// 185.742 us; speedup vs baseline: 1.1263x; 1.0136x over previous
//
#include <hip/hip_runtime.h>
#include <hip/hip_bf16.h>

#define B_  2
#define S_  2048
#define H_  1024
#define NH_ 16
#define HD_ 64
#define T_  (B_*S_)     // 4096 tokens
#define H3_ (3*H_)      // 3072

typedef float  floatx4 __attribute__((ext_vector_type(4)));
typedef __bf16 bf16x8  __attribute__((ext_vector_type(8)));

__device__ inline unsigned short f2bf_rn(float f) {
    union { float f; unsigned int u; } v; v.f = f;
    unsigned int u = v.u;
    u += 0x7fffu + ((u >> 16) & 1u);
    return (unsigned short)(u >> 16);
}
__device__ inline floatx4 fzero4() { floatx4 v; v[0]=0.f; v[1]=0.f; v[2]=0.f; v[3]=0.f; return v; }

__device__ inline float bf2f(unsigned short u) {
    union { unsigned int i; float f; } x; x.i = ((unsigned int)u) << 16; return x.f;
}

// pack two f32 -> one u32 of two bf16 (lo = src0), RNE; no builtin on gfx950 -> inline asm
__device__ inline unsigned int cvtpk_bf16(float lo, float hi) {
    unsigned int r;
    asm("v_cvt_pk_bf16_f32 %0, %1, %2" : "=v"(r) : "v"(lo), "v"(hi));
    return r;
}

// async global->LDS, 16B per lane; LDS dest = wave-uniform base + lane*16
__device__ inline void gload_lds16(const unsigned short* g, unsigned short* l) {
    __builtin_amdgcn_global_load_lds((const __attribute__((address_space(1))) unsigned int*)g,
                                     (__attribute__((address_space(3))) unsigned int*)l,
                                     16, 0, 0);
}

// ---------------------------------------------------------------- fused preprocessing: weight cast+transpose AND LayerNorm
// blocks 0..1023: cvt (768 qkvw tiles + 256 ow tiles); blocks 1024..5119: LN (one token each).
#define TLD 72
__global__ __launch_bounds__(256) void pre_k(const float* __restrict__ qkvw,
                                             const float* __restrict__ ow,
                                             unsigned short* __restrict__ qkvwT,
                                             unsigned short* __restrict__ owT,
                                             const float* __restrict__ x,
                                             const float* __restrict__ nw,
                                             const float* __restrict__ nb,
                                             unsigned short* __restrict__ xn) {
    const int tid = threadIdx.x;
    if (blockIdx.x < 1024) {
        __shared__ unsigned short Ts[64 * TLD];
        int id = blockIdx.x;
        const float* W; unsigned short* Wt; int N, nbs, kb;
        if (id < 768) { W = qkvw; Wt = qkvwT; N = H3_; nbs = (id % 48) * 64; kb = (id / 48) * 64; }
        else { id -= 768; W = ow; Wt = owT; N = H_; nbs = (id % 16) * 64; kb = (id / 16) * 64; }
        const int K = H_;
        #pragma unroll
        for (int p = 0; p < 4; p++) {
            const int krow = kb + p * 16 + (tid >> 4);
            const int ncol = (tid & 15) * 4;
            const float4 w = *reinterpret_cast<const float4*>(&W[(size_t)krow * N + nbs + ncol]);
            Ts[(ncol + 0) * TLD + p * 16 + (tid >> 4)] = f2bf_rn(w.x);
            Ts[(ncol + 1) * TLD + p * 16 + (tid >> 4)] = f2bf_rn(w.y);
            Ts[(ncol + 2) * TLD + p * 16 + (tid >> 4)] = f2bf_rn(w.z);
            Ts[(ncol + 3) * TLD + p * 16 + (tid >> 4)] = f2bf_rn(w.w);
        }
        __syncthreads();
        #pragma unroll
        for (int p = 0; p < 2; p++) {
            const int n = (tid >> 3) + p * 32;
            const int k8 = (tid & 7) * 8;
            const uint4 v = *reinterpret_cast<const uint4*>(&Ts[n * TLD + k8]);
            *reinterpret_cast<uint4*>(&Wt[(size_t)(nbs + n) * K + kb + k8]) = v;
        }
    } else {
        const int t = blockIdx.x - 1024;
        const float4 v = reinterpret_cast<const float4*>(x + (size_t)t * H_)[tid];
        float s  = v.x + v.y + v.z + v.w;
        float s2 = v.x*v.x + v.y*v.y + v.z*v.z + v.w*v.w;
        for (int off = 32; off > 0; off >>= 1) {
            s  += __shfl_down(s,  off, 64);
            s2 += __shfl_down(s2, off, 64);
        }
        __shared__ float red[8];
        const int wave = tid >> 6, lane = tid & 63;
        if (lane == 0) { red[wave] = s; red[4 + wave] = s2; }
        __syncthreads();
        if (tid == 0) {
            red[0] = red[0] + red[1] + red[2] + red[3];
            red[4] = red[4] + red[5] + red[6] + red[7];
        }
        __syncthreads();
        const float mean = red[0] * (1.f / H_);
        const float var  = red[4] * (1.f / H_) - mean * mean;
        const float rstd = rsqrtf(var + 1e-5f);
        const float4 wv = reinterpret_cast<const float4*>(nw)[tid];
        const float4 bv = reinterpret_cast<const float4*>(nb)[tid];
        ushort4 o = make_ushort4(f2bf_rn((v.x - mean) * rstd * wv.x + bv.x),
                                 f2bf_rn((v.y - mean) * rstd * wv.y + bv.y),
                                 f2bf_rn((v.z - mean) * rstd * wv.z + bv.z),
                                 f2bf_rn((v.w - mean) * rstd * wv.w + bv.w));
        reinterpret_cast<ushort4*>(xn + (size_t)t * H_)[tid] = o;
    }
}

// ---------------------------------------------------------------- QKV GEMM: 128x64 tiles (proj-proven shape) -> 1536 blocks,
// 6 blocks/CU (was 768 = 3/CU, occupancy 13.8%, all pipes <25% = latency-bound). 2D x-major grid keeps
// the r7-measured locality (per-XCD-resident B-panels + lockstep A-walk; r8's swizzle was worse).
// BN=64 -> head-group block-uniform -> simpler rotary epilogue. LDS 24.5KB, acc[2][4]/wave.
__global__ __launch_bounds__(256) void gemm_qkv_k(const unsigned short* __restrict__ A,
                                                  const unsigned short* __restrict__ Bt,
                                                  const float* __restrict__ bias,
                                                  unsigned short* __restrict__ Qo,
                                                  unsigned short* __restrict__ Ko,
                                                  unsigned short* __restrict__ Vto) {
    __shared__ unsigned short As0[128 * 32], As1[128 * 32];
    __shared__ unsigned short Bs0[ 64 * 32], Bs1[ 64 * 32];

    const int tid  = threadIdx.x;
    const int lane = tid & 63;
    const int wave = tid >> 6;              // 0..3, owns rows wave*32..+31
    const int mBase = blockIdx.y * 128;
    const int nBase = blockIdx.x * 64;
    const int K = H_;

    const int srow = lane >> 2;             // 0..15
    const int scol = (lane & 3) * 8;        // 0,8,16,24
    const int mrow = lane & 15;
    const int koff = (lane >> 4) * 8;

    floatx4 acc[2][4];
    #pragma unroll
    for (int i = 0; i < 2; i++)
        #pragma unroll
        for (int j = 0; j < 4; j++) acc[i][j] = fzero4();

    for (int kb = 0; kb < K; kb += 64) {
        __syncthreads();
        #pragma unroll
        for (int p = 0; p < 2; p++) {
            const int r = wave * 16 + p * 64;
            const size_t ga = (size_t)(mBase + r + srow) * K + kb + scol;
            gload_lds16(&A[ga],      &As0[r * 32]);
            gload_lds16(&A[ga + 32], &As1[r * 32]);
        }
        {
            const int r = wave * 16;
            const size_t gb = (size_t)(nBase + r + srow) * K + kb + scol;
            gload_lds16(&Bt[gb],      &Bs0[r * 32]);
            gload_lds16(&Bt[gb + 32], &Bs1[r * 32]);
        }
        __syncthreads();

        #pragma unroll
        for (int half = 0; half < 2; half++) {
            const unsigned short* As = half ? As1 : As0;
            const unsigned short* Bs = half ? Bs1 : Bs0;
            bf16x8 afrag[2], bfrag[4];
            #pragma unroll
            for (int mt = 0; mt < 2; mt++)
                afrag[mt] = *reinterpret_cast<const bf16x8*>(&As[(wave * 32 + mt * 16 + mrow) * 32 + koff]);
            #pragma unroll
            for (int nt = 0; nt < 4; nt++)
                bfrag[nt] = *reinterpret_cast<const bf16x8*>(&Bs[(nt * 16 + mrow) * 32 + koff]);
            #pragma unroll
            for (int mt = 0; mt < 2; mt++)
                #pragma unroll
                for (int nt = 0; nt < 4; nt++)
                    acc[mt][nt] = __builtin_amdgcn_mfma_f32_16x16x32_bf16(afrag[mt], bfrag[nt], acc[mt][nt], 0, 0, 0);
        }
    }

    const int col0 = lane & 15;
    const int r0   = (lane >> 4) * 4;
    const int hg   = nBase >> 6;               // block-uniform head index (0..47)
    const int sec  = hg >> 4;                  // 0=q 1=k 2=v
    const int h    = hg & 15;

    float bs[4];
    #pragma unroll
    for (int nt = 0; nt < 4; nt++) bs[nt] = bias[nBase + nt * 16 + col0];

    if (sec < 2) {
        unsigned short* dst = (sec == 0) ? Qo : Ko;
        const float if0 = __expf((float)col0        * (-0.2878231366f));   // j = col0
        const float if1 = __expf((float)(16 + col0) * (-0.2878231366f));   // j = 16+col0
        #pragma unroll
        for (int mt = 0; mt < 2; mt++) {
            #pragma unroll
            for (int reg = 0; reg < 4; reg++) {
                const int t  = mBase + wave * 32 + mt * 16 + r0 + reg;
                const int bb = t >> 11;
                const int s  = t & (S_ - 1);
                float sn0, cs0, sn1, cs1;
                __sincosf((float)s * if0, &sn0, &cs0);
                __sincosf((float)s * if1, &sn1, &cs1);
                const float v0 = acc[mt][0][reg] + bs[0];   // d = col0
                const float v1 = acc[mt][1][reg] + bs[1];   // d = 16+col0
                const float v2 = acc[mt][2][reg] + bs[2];   // d = 32+col0
                const float v3 = acc[mt][3][reg] + bs[3];   // d = 48+col0
                const float o0 = v0 * cs0 - v2 * sn0;
                const float o1 = v1 * cs1 - v3 * sn1;
                const float o2 = v2 * cs0 + v0 * sn0;
                const float o3 = v3 * cs1 + v1 * sn1;
                const size_t rb = ((size_t)(bb * NH_ + h) * S_ + s) * HD_;
                dst[rb +      col0] = f2bf_rn(o0);
                dst[rb + 16 + col0] = f2bf_rn(o1);
                dst[rb + 32 + col0] = f2bf_rn(o2);
                dst[rb + 48 + col0] = f2bf_rn(o3);
            }
        }
    } else {
        #pragma unroll
        for (int mt = 0; mt < 2; mt++) {
            const int t0 = mBase + wave * 32 + mt * 16 + r0;   // 4 consecutive tokens, 4-aligned
            const int bb = t0 >> 11;
            const int s0 = t0 & (S_ - 1);
            #pragma unroll
            for (int nt = 0; nt < 4; nt++) {
                const int d = nt * 16 + col0;
                ushort4 o;
                o.x = f2bf_rn(acc[mt][nt][0] + bs[nt]);
                o.y = f2bf_rn(acc[mt][nt][1] + bs[nt]);
                o.z = f2bf_rn(acc[mt][nt][2] + bs[nt]);
                o.w = f2bf_rn(acc[mt][nt][3] + bs[nt]);
                *reinterpret_cast<ushort4*>(&Vto[((size_t)(bb * NH_ + h) * HD_ + d) * S_ + s0]) = o;
            }
        }
    }
}

// ---------------------------------------------------------------- proj GEMM: 128x64 tiles, 1D grid + XCD swizzle (r8 config)
__global__ __launch_bounds__(256) void gemm_proj_k(const unsigned short* __restrict__ A,
                                                   const unsigned short* __restrict__ Bt,
                                                   const float* __restrict__ bias,
                                                   float* __restrict__ Cf,
                                                   int M, int N, int K) {
    __shared__ unsigned short As0[128 * 32], As1[128 * 32];
    __shared__ unsigned short Bs0[ 64 * 32], Bs1[ 64 * 32];

    const int tid  = threadIdx.x;
    const int lane = tid & 63;
    const int wave = tid >> 6;              // 0..3, owns rows wave*32..+31
    const int id  = blockIdx.x;
    const int nid = (id & 7) * 64 + (id >> 3);
    const int mBase = (nid >> 4) * 128;
    const int nBase = (nid & 15) * 64;

    const int srow = lane >> 2;             // 0..15
    const int scol = (lane & 3) * 8;        // 0,8,16,24
    const int mrow = lane & 15;
    const int koff = (lane >> 4) * 8;

    floatx4 acc[2][4];
    #pragma unroll
    for (int i = 0; i < 2; i++)
        #pragma unroll
        for (int j = 0; j < 4; j++) acc[i][j] = fzero4();

    for (int kb = 0; kb < K; kb += 64) {
        __syncthreads();
        #pragma unroll
        for (int p = 0; p < 2; p++) {
            const int r = wave * 16 + p * 64;
            const size_t ga = (size_t)(mBase + r + srow) * K + kb + scol;
            gload_lds16(&A[ga],      &As0[r * 32]);
            gload_lds16(&A[ga + 32], &As1[r * 32]);
        }
        {
            const int r = wave * 16;
            const size_t gb = (size_t)(nBase + r + srow) * K + kb + scol;
            gload_lds16(&Bt[gb],      &Bs0[r * 32]);
            gload_lds16(&Bt[gb + 32], &Bs1[r * 32]);
        }
        __syncthreads();

        #pragma unroll
        for (int half = 0; half < 2; half++) {
            const unsigned short* As = half ? As1 : As0;
            const unsigned short* Bs = half ? Bs1 : Bs0;
            bf16x8 afrag[2], bfrag[4];
            #pragma unroll
            for (int mt = 0; mt < 2; mt++)
                afrag[mt] = *reinterpret_cast<const bf16x8*>(&As[(wave * 32 + mt * 16 + mrow) * 32 + koff]);
            #pragma unroll
            for (int nt = 0; nt < 4; nt++)
                bfrag[nt] = *reinterpret_cast<const bf16x8*>(&Bs[(nt * 16 + mrow) * 32 + koff]);
            #pragma unroll
            for (int mt = 0; mt < 2; mt++)
                #pragma unroll
                for (int nt = 0; nt < 4; nt++)
                    acc[mt][nt] = __builtin_amdgcn_mfma_f32_16x16x32_bf16(afrag[mt], bfrag[nt], acc[mt][nt], 0, 0, 0);
        }
    }

    const int col0 = lane & 15;
    const int r0   = (lane >> 4) * 4;
    #pragma unroll
    for (int mt = 0; mt < 2; mt++) {
        #pragma unroll
        for (int nt = 0; nt < 4; nt++) {
            const int gcol = nBase + nt * 16 + col0;
            const float bsv = bias[gcol];
            #pragma unroll
            for (int reg = 0; reg < 4; reg++) {
                const int grow = mBase + wave * 32 + mt * 16 + r0 + reg;
                Cf[(size_t)grow * N + gcol] = acc[mt][nt][reg] + bsv;
            }
        }
    }
}

// ---------------------------------------------------------------- flash attention: in-register P + LDS mask-bias table
// (unchanged from r7 — in-register P via swapped QK + key-permuted K staging, ones-A MFMA denominator,
// LDS bias table, setprio around PV cluster)
#define ALD 72
#define SCL2 0.1803368801f      /* 0.125 * log2(e) */
#define MNEG -14427.0f          /* -10000 * log2(e), causal fill */

__global__ __launch_bounds__(256, 4) void attn_k(const unsigned short* __restrict__ Q,
                                                 const unsigned short* __restrict__ Kg,
                                                 const unsigned short* __restrict__ Vt,
                                                 const int* __restrict__ mask,
                                                 unsigned short* __restrict__ ctx) {
    const int id = blockIdx.x;              // 0..1023
    const int bh = id & 31;                 // id%8 fixed per bh -> XCD locality
    const int v  = 31 - (id >> 5);          // q-tile index; most work first
    const int b  = bh >> 4;
    const int h  = bh & 15;
    const int tid  = threadIdx.x;
    const int lane = tid & 63;
    const int wave = tid >> 6;

    __shared__ unsigned short Ks [2][64 * ALD];   // 18.4 KB (key-permuted rows)
    __shared__ unsigned short Vts[2][64 * ALD];   // 18.4 KB (natural key order)
    __shared__ unsigned short Mb [S_];            //  4.0 KB bf16 mask-bias per key

    const size_t base = (size_t)bh * S_ * HD_;
    const int qbase = v * 64 + wave * 16;
    const int r16  = lane & 15;             // A-row / output-col lane index
    const int koff = (lane >> 4) * 8;       // d-offset in fragments / key-offset in PV reads
    const int g8   = (lane >> 4) * 8;       // key-group base for St quads
    const int qcol = qbase + r16;           // this lane's q row (output column)

    // ---- mask-bias table: 8 keys per thread, one b128 store; visible after first barrier
    {
        const int k0 = tid * 8;
        const int4 ma = *reinterpret_cast<const int4*>(&mask[b * S_ + k0]);
        const int4 mc = *reinterpret_cast<const int4*>(&mask[b * S_ + k0 + 4]);
        union { unsigned short us[8]; uint4 q; } pk;
        pk.us[0] = f2bf_rn((1.f - (float)ma.x) * MNEG);
        pk.us[1] = f2bf_rn((1.f - (float)ma.y) * MNEG);
        pk.us[2] = f2bf_rn((1.f - (float)ma.z) * MNEG);
        pk.us[3] = f2bf_rn((1.f - (float)ma.w) * MNEG);
        pk.us[4] = f2bf_rn((1.f - (float)mc.x) * MNEG);
        pk.us[5] = f2bf_rn((1.f - (float)mc.y) * MNEG);
        pk.us[6] = f2bf_rn((1.f - (float)mc.z) * MNEG);
        pk.us[7] = f2bf_rn((1.f - (float)mc.w) * MNEG);
        *reinterpret_cast<uint4*>(&Mb[k0]) = pk.q;
    }

    const bf16x8 qf0 = *reinterpret_cast<const bf16x8*>(&Q[base + (size_t)(qbase + r16) * HD_ + koff]);
    const bf16x8 qf1 = *reinterpret_cast<const bf16x8*>(&Q[base + (size_t)(qbase + r16) * HD_ + 32 + koff]);

    bf16x8 onesA;
    #pragma unroll
    for (int q = 0; q < 8; q++) onesA[q] = (__bf16)1.f;

    floatx4 Ot[4];                           // O^T: lane holds O^T[d=db*16+(lane>>4)*4+reg][q=qcol]
    #pragma unroll
    for (int db = 0; db < 4; db++) Ot[db] = fzero4();
    floatx4 Lacc = fzero4();                 // every row = column sum of P (ones-A MFMA)

    const int srow = tid >> 3;          // 0..31
    const int scol = (tid & 7) * 8;
    // key permutation within a 32-window: row r holds key pi(r)
    const int pi = ((srow & 12) << 1) | (srow & 3) | (((srow >> 4) & 1) << 2);

    // named prefetch registers for 2 tiles (no runtime-indexed arrays -> no scratch)
    uint4 k00, k01, k10, k11, v00, v01, v10, v11;
#define PF_TILE(TT, KR0, KR1, VR0, VR1) do {                                                   \
        const int kb_ = (TT) * 64;                                                             \
        KR0 = *reinterpret_cast<const uint4*>(&Kg[base + (size_t)(kb_ + pi)      * HD_ + scol]); \
        KR1 = *reinterpret_cast<const uint4*>(&Kg[base + (size_t)(kb_ + 32 + pi) * HD_ + scol]); \
        VR0 = *reinterpret_cast<const uint4*>(&Vt[base + (size_t)srow        * S_ + kb_ + scol]);  \
        VR1 = *reinterpret_cast<const uint4*>(&Vt[base + (size_t)(srow + 32) * S_ + kb_ + scol]);  \
    } while (0)
#define PREFETCH_MACRO(MI) do {                                                                \
        const int t0_ = min(2 * (MI), v);                                                      \
        const int t1_ = min(2 * (MI) + 1, v);                                                  \
        PF_TILE(t0_, k00, k01, v00, v01);                                                      \
        PF_TILE(t1_, k10, k11, v10, v11);                                                      \
    } while (0)

    const int nmac = (v + 2) >> 1;
    PREFETCH_MACRO(0);

    for (int mi = 0; mi < nmac; mi++) {
        if (mi) __syncthreads();                       // WAR: prior macro's LDS reads done
        *reinterpret_cast<uint4*>(&Ks [0][ srow       * ALD + scol]) = k00;
        *reinterpret_cast<uint4*>(&Ks [0][(srow + 32) * ALD + scol]) = k01;
        *reinterpret_cast<uint4*>(&Ks [1][ srow       * ALD + scol]) = k10;
        *reinterpret_cast<uint4*>(&Ks [1][(srow + 32) * ALD + scol]) = k11;
        *reinterpret_cast<uint4*>(&Vts[0][ srow       * ALD + scol]) = v00;
        *reinterpret_cast<uint4*>(&Vts[0][(srow + 32) * ALD + scol]) = v01;
        *reinterpret_cast<uint4*>(&Vts[1][ srow       * ALD + scol]) = v10;
        *reinterpret_cast<uint4*>(&Vts[1][(srow + 32) * ALD + scol]) = v11;
        __syncthreads();                               // staged tiles + (mi==0) Mb table visible
        if (mi + 1 < nmac) PREFETCH_MACRO(mi + 1);

        #pragma unroll
        for (int half = 0; half < 2; half++) {
            const int kt = 2 * mi + half;
            if (half && kt > v) continue;              // wave-uniform skip (odd tile count)
            const int kb = kt * 64;
            const unsigned short* ks = Ks [half];
            const unsigned short* vs = Vts[half];

            // ---- per-tile bias: four 8B broadcast LDS reads, latency hidden under QK
            const unsigned short* mbp = &Mb[kb + g8];
            const ushort4 b00 = *reinterpret_cast<const ushort4*>(mbp);        // w0 ab0
            const ushort4 b01 = *reinterpret_cast<const ushort4*>(mbp + 4);    // w0 ab1
            const ushort4 b10 = *reinterpret_cast<const ushort4*>(mbp + 32);   // w1 ab0
            const ushort4 b11 = *reinterpret_cast<const ushort4*>(mbp + 36);   // w1 ab1

            #pragma unroll
            for (int w = 0; w < 2; w++) {              // two 32-key windows
                float p[2][4];
                #pragma unroll
                for (int ab = 0; ab < 2; ab++) {
                    const int nt = w * 2 + ab;
                    // St = K·Q^T over permuted K rows; quad reg -> key kb + w*32 + ab*4 + 8g + reg
                    const bf16x8 kf0 = *reinterpret_cast<const bf16x8*>(&ks[(nt * 16 + r16) * ALD + koff]);
                    const bf16x8 kf1 = *reinterpret_cast<const bf16x8*>(&ks[(nt * 16 + r16) * ALD + 32 + koff]);
                    floatx4 c = fzero4();
                    c = __builtin_amdgcn_mfma_f32_16x16x32_bf16(kf0, qf0, c, 0, 0, 0);
                    c = __builtin_amdgcn_mfma_f32_16x16x32_bf16(kf1, qf1, c, 0, 0, 0);
                    const ushort4 bb = w ? (ab ? b11 : b10) : (ab ? b01 : b00);
                    const int kbase = kb + w * 32 + ab * 4 + g8;
                    float sc0 = c[0] * SCL2 + bf2f(bb.x);
                    float sc1 = c[1] * SCL2 + bf2f(bb.y);
                    float sc2 = c[2] * SCL2 + bf2f(bb.z);
                    float sc3 = c[3] * SCL2 + bf2f(bb.w);
                    if (kt == v) {                     // causal on diagonal tile only
                        if (kbase + 0 > qcol) sc0 = MNEG;
                        if (kbase + 1 > qcol) sc1 = MNEG;
                        if (kbase + 2 > qcol) sc2 = MNEG;
                        if (kbase + 3 > qcol) sc3 = MNEG;
                    }
                    p[ab][0] = exp2f(sc0);
                    p[ab][1] = exp2f(sc1);
                    p[ab][2] = exp2f(sc2);
                    p[ab][3] = exp2f(sc3);
                }
                // pack P fragment: keys w*32 + 8g + {0..7} in order
                union { uint4 u; bf16x8 v; } pf;
                pf.u.x = cvtpk_bf16(p[0][0], p[0][1]);
                pf.u.y = cvtpk_bf16(p[0][2], p[0][3]);
                pf.u.z = cvtpk_bf16(p[1][0], p[1][1]);
                pf.u.w = cvtpk_bf16(p[1][2], p[1][3]);
                // PV: O^T += V^T · P^T (V natural key order, contiguous reads); L via ones-A MFMA
                __builtin_amdgcn_s_setprio(1);
                #pragma unroll
                for (int db = 0; db < 4; db++) {
                    const bf16x8 vf = *reinterpret_cast<const bf16x8*>(&vs[(db * 16 + r16) * ALD + w * 32 + koff]);
                    Ot[db] = __builtin_amdgcn_mfma_f32_16x16x32_bf16(vf, pf.v, Ot[db], 0, 0, 0);
                }
                Lacc = __builtin_amdgcn_mfma_f32_16x16x32_bf16(onesA, pf.v, Lacc, 0, 0, 0);
                __builtin_amdgcn_s_setprio(0);
            }
        }
    }
#undef PREFETCH_MACRO
#undef PF_TILE

    // epilogue: Lacc rows all equal the full column sum — no cross-lane reduce needed
    const float rl = 1.f / Lacc[0];
    const int r4 = (lane >> 4) * 4;
    #pragma unroll
    for (int db = 0; db < 4; db++) {
        ushort4 o;
        o.x = f2bf_rn(Ot[db][0] * rl);
        o.y = f2bf_rn(Ot[db][1] * rl);
        o.z = f2bf_rn(Ot[db][2] * rl);
        o.w = f2bf_rn(Ot[db][3] * rl);
        *reinterpret_cast<ushort4*>(&ctx[((size_t)b * S_ + qcol) * H_ + h * HD_ + db * 16 + r4]) = o;
    }
}

// ---------------------------------------------------------------- launch
extern "C" void kernel_launch(void* const* d_in, const int* in_sizes, int n_in,
                              void* d_out, int out_size, void* d_ws, size_t ws_size,
                              hipStream_t stream) {
    const float* x     = (const float*)d_in[0];
    const int*   mask  = (const int*)d_in[1];
    const float* normw = (const float*)d_in[2];
    const float* normb = (const float*)d_in[3];
    const float* qkvw  = (const float*)d_in[4];
    const float* qkvb  = (const float*)d_in[5];
    const float* ow    = (const float*)d_in[6];
    const float* ob    = (const float*)d_in[7];
    float* out = (float*)d_out;

    char* ws = (char*)d_ws;
    unsigned short* xn_bf   = (unsigned short*)(ws);                      //  8 MB
    unsigned short* qkvwT   = (unsigned short*)(ws + (8ull  << 20));      //  6 MB
    unsigned short* owT     = (unsigned short*)(ws + (14ull << 20));      //  2 MB
    unsigned short* Qb      = (unsigned short*)(ws + (16ull << 20));      //  8 MB [bh][s][d]
    unsigned short* Kb      = (unsigned short*)(ws + (24ull << 20));      //  8 MB [bh][s][d]
    unsigned short* Vtb     = (unsigned short*)(ws + (32ull << 20));      //  8 MB [bh][d][s]
    unsigned short* ctx_bf  = (unsigned short*)(ws + (40ull << 20));      //  8 MB

    pre_k<<<1024 + T_, 256, 0, stream>>>(qkvw, ow, qkvwT, owT, x, normw, normb, xn_bf);
    gemm_qkv_k<<<dim3(H3_ / 64, T_ / 128), 256, 0, stream>>>(xn_bf, qkvwT, qkvb, Qb, Kb, Vtb);
    attn_k<<<1024, 256, 0, stream>>>(Qb, Kb, Vtb, mask, ctx_bf);
    gemm_proj_k<<<512, 256, 0, stream>>>(ctx_bf, owT, ob, out, T_, H_, H_);
}